// Round 7
// baseline (221.058 us; speedup 1.0000x reference)
//
#include <hip/hip_runtime.h>

// Discriminator pipeline, R7.
// R6 showed k1 (61us) is VALU-issue-bound on conv1-recompute+bf16-pack
// (~24 VALU per MFMA). R7 hoists conv1 into kprep: x1 = conv1+lrelu stored
// ONCE as bf16 [samp][hw=90][ch=64] (B-frag layout), so k1's inner loop is
// 1 global_load_dwordx4 + 1 MFMA. XCD swizzle: k1 grid (32 chunks, 50 pos)
// -> linear id % 8 == chunk % 8, so chunk's x1 slab stays in that XCD's L2.
// ws_size unknown -> 1/2/4/8 sample passes so x1 always fits (x1 region
// aliases y2b/y3b, dead until k2).
//  kprep: conv1+lrelu -> x1 bf16; pass0 also: lc1 A-frags + zero stats.
//  k1  : lc1 pure-load MFMA GEMM -> y1b bf16 + BN1 stats.
//  k2  : lc2 VALU fp32, BN1 folded on bf16 uint2 loads -> y2b + BN2.
//  k3  : lc3 same -> y3b + BN3.
//  k4  : BN3 + bf16 LDS transpose -> out[8192][384] f32.

typedef float  f32x4 __attribute__((ext_vector_type(4)));
typedef float  f32x2 __attribute__((ext_vector_type(2)));
typedef short  bf16x8 __attribute__((ext_vector_type(8)));

union FR  { int4 i4; bf16x8 bf; unsigned u[4]; };

#define LRELU(v) fmaxf((v), 0.01f * (v))

static __device__ inline unsigned bfr(float f) {              // RNE fp32->bf16
    unsigned u = __float_as_uint(f);
    return (u + 0x7fffu + ((u >> 16) & 1u)) >> 16;
}
static __device__ inline unsigned short bfr16(float f) { return (unsigned short)bfr(f); }
static __device__ inline float ubf(unsigned lo16) { return __uint_as_float(lo16 << 16); }

#if __has_builtin(__builtin_elementwise_fma)
static __device__ inline f32x2 pk_fma(f32x2 a, f32x2 b, f32x2 c) { return __builtin_elementwise_fma(a, b, c); }
#else
static __device__ inline f32x2 pk_fma(f32x2 a, f32x2 b, f32x2 c) { return a * b + c; }
#endif
static __device__ inline f32x2 pk_lrelu(f32x2 v) {
#if __has_builtin(__builtin_elementwise_max)
    return __builtin_elementwise_max(v, v * 0.01f);
#else
    f32x2 r; r.x = LRELU(v.x); r.y = LRELU(v.y); return r;
#endif
}
static __device__ inline float aload(float* p) {
    return __hip_atomic_load(p, __ATOMIC_RELAXED, __HIP_MEMORY_SCOPE_AGENT);
}

// ---------------- kprep: conv1 -> x1 bf16 (+ afg + stats on pass 0) ----------------
union PrepSM { float imgP[16][110]; float wt[9216]; };   // 36 KB

__global__ __launch_bounds__(256) void kprep(
    const float* __restrict__ imgp,  // image + pass offset*90
    const float* __restrict__ cw,    // conv1_w [64*4]
    const float* __restrict__ cb,    // conv1_b [64]
    const float* __restrict__ lw1,   // lc1_w [16][64][450]
    unsigned* __restrict__ x1u,      // bf16-pair [sppLocal][90][32]
    int4* __restrict__ afg1, float* __restrict__ stats,
    int nA, int doAux)
{
    __shared__ PrepSM sm;
    const int bx = blockIdx.x, tid = threadIdx.x;

    if (bx < nA) {
        const int sb = bx * 16;                      // local sample base (16 samples)
        for (int e = tid; e < 1760; e += 256) ((float*)sm.imgP)[e] = 0.0f;
        __syncthreads();
        for (int e = tid; e < 1440; e += 256) {
            int s = e / 90, hw = e - s * 90;
            int r = hw / 9, c = hw - r * 9;
            sm.imgP[s][r * 10 + c] = imgp[(size_t)sb * 90 + e];
        }
        __syncthreads();

        const int chp = tid & 31, sidx = tid >> 5;
        const int ch0 = 2 * chp;
        f32x2 w00 = {cw[ch0 * 4 + 0], cw[ch0 * 4 + 4]};
        f32x2 w01 = {cw[ch0 * 4 + 1], cw[ch0 * 4 + 5]};
        f32x2 w10 = {cw[ch0 * 4 + 2], cw[ch0 * 4 + 6]};
        f32x2 w11 = {cw[ch0 * 4 + 3], cw[ch0 * 4 + 7]};
        f32x2 bb  = {cb[ch0], cb[ch0 + 1]};

        #pragma unroll
        for (int ss = 0; ss < 2; ++ss) {
            const int s = sidx + 8 * ss;
            const float* ip = sm.imgP[s];
            unsigned* dst = x1u + (size_t)(sb + s) * 2880 + chp;   // (samp*90+hw)*32+chp
            #pragma unroll 2
            for (int r = 0; r < 10; ++r) {
                #pragma unroll
                for (int c = 0; c < 9; ++c) {
                    f32x2 v = bb;
                    v = pk_fma((f32x2)ip[r * 10 + c],      w00, v);
                    v = pk_fma((f32x2)ip[r * 10 + c + 1],  w01, v);
                    v = pk_fma((f32x2)ip[r * 10 + c + 10], w10, v);
                    v = pk_fma((f32x2)ip[r * 10 + c + 11], w11, v);
                    v = pk_lrelu(v);
                    dst[(r * 9 + c) * 32] = bfr(v.x) | (bfr(v.y) << 16);
                }
            }
        }
        return;
    }
    if (!doAux) return;

    const int b2 = bx - nA;
    if (b2 < 50) {                                   // lc1 A-fragments
        const int pos = b2;
        for (int e = tid; e < 9216; e += 256) {
            int pair = e / 9, t = e - 9 * pair;
            sm.wt[e] = lw1[pair * 450 + pos * 9 + t];
        }
        __syncthreads();
        for (int e = tid; e < 1152; e += 256) {
            int l = e & 63, ht = e >> 6;
            int h = (ht >= 9) ? 1 : 0, t = ht - 9 * h;
            int q = l >> 4, o = l & 15;
            unsigned uu[4];
            #pragma unroll
            for (int p = 0; p < 4; ++p) {
                int c0 = 32 * h + 8 * q + 2 * p;
                float a0 = sm.wt[(o * 64 + c0) * 9 + t];
                float a1 = sm.wt[(o * 64 + c0 + 1) * 9 + t];
                uu[p] = bfr(a0) | (bfr(a1) << 16);
            }
            int4 st = { (int)uu[0], (int)uu[1], (int)uu[2], (int)uu[3] };
            afg1[pos * 1152 + e] = st;
        }
    } else if (tid < 64) stats[tid] = 0.0f;
}

// ---------------- k1: lc1 pure-load MFMA GEMM ----------------
__global__ __launch_bounds__(256) void k1_lc1(
    const int4* __restrict__ x1v,    // [sppLocal*90*8] int4 (8 bf16 each)
    const int4* __restrict__ afg,    // lc1 A-frags
    const float* __restrict__ lb,    // lc1_b [16*50]
    unsigned short* __restrict__ y1b,// bf16 [800][8192]
    float* __restrict__ stats,       // [0..31] sum16/sq16
    int sampOff)                     // pass offset (absolute)
{
    __shared__ int4  AfL[1152];      // 18432 B
    __shared__ float bl[16];
    __shared__ float red[32];

    const int pos = blockIdx.y;           // 0..49
    const int oh = pos / 5, ow = pos % 5;
    const int tid = threadIdx.x;
    const int wv = tid >> 6, lane = tid & 63;
    const int lane15 = lane & 15, q = lane >> 4;

    for (int e = tid; e < 1152; e += 256) AfL[e] = afg[pos * 1152 + e];
    if (tid < 16) bl[tid] = lb[tid * 50 + pos];
    if (tid < 32) red[tid] = 0.0f;
    __syncthreads();

    const int sLoc = blockIdx.x * 256 + wv * 64;     // local (this pass)
    const int sAbs = sampOff + sLoc;                 // absolute (for y1b/stats)

    int sOff[4];
    #pragma unroll
    for (int g = 0; g < 4; ++g)
        sOff[g] = (sLoc + g * 16 + lane15) * 720 + q;  // int4 units: samp*90*8 + q

    f32x4 acc[4];
    #pragma unroll
    for (int g = 0; g < 4; ++g) acc[g] = (f32x4){0.f, 0.f, 0.f, 0.f};

    #pragma unroll
    for (int t = 0; t < 9; ++t) {
        const int ti = t / 3, tj = t % 3;
        const int r = oh + ti - 1, c2 = 2 * ow + tj - 1;
        if (r >= 0 && r < 10 && c2 >= 0 && c2 < 9) {         // block-uniform
            const int hw8 = (r * 9 + c2) * 8;
            #pragma unroll
            for (int h = 0; h < 2; ++h) {
                FR fa; fa.i4 = AfL[(h * 9 + t) * 64 + lane];
                #pragma unroll
                for (int g = 0; g < 4; ++g) {
                    FR fb; fb.i4 = x1v[sOff[g] + hw8 + h * 4];
                    acc[g] = __builtin_amdgcn_mfma_f32_16x16x32_bf16(fa.bf, fb.bf, acc[g], 0, 0, 0);
                }
            }
        }
    }

    float so[4] = {0, 0, 0, 0}, sq[4] = {0, 0, 0, 0};
    #pragma unroll
    for (int g = 0; g < 4; ++g)
        #pragma unroll
        for (int r = 0; r < 4; ++r) {
            int o = q * 4 + r;
            float v = acc[g][r] + bl[o];
            v = LRELU(v);
            y1b[(size_t)(o * 50 + pos) * 8192 + sAbs + g * 16 + lane15] = bfr16(v);
            so[r] += v; sq[r] += v * v;
        }
    #pragma unroll
    for (int r = 0; r < 4; ++r) {
        #pragma unroll
        for (int m = 1; m < 16; m <<= 1) {
            so[r] += __shfl_xor(so[r], m, 16);
            sq[r] += __shfl_xor(sq[r], m, 16);
        }
        if (lane15 == 0) {
            int o = q * 4 + r;
            atomicAdd(&red[o], so[r]);
            atomicAdd(&red[16 + o], sq[r]);
        }
    }
    __syncthreads();
    if (tid < 32) atomicAdd(&stats[tid], red[tid]);
}

// ---------------- k2: lc2 (VALU fp32, bf16 uint2 IO) ----------------
__global__ __launch_bounds__(256) void k2_lc2(
    const unsigned short* __restrict__ y1b,
    const float* __restrict__ lw2, const float* __restrict__ lb2,
    const float* __restrict__ g1, const float* __restrict__ be1,
    unsigned short* __restrict__ y2b, float* __restrict__ stats)
{
    __shared__ float wld[512];
    __shared__ float a1[16], b1[16], bl[8], red[16];

    const int unit = blockIdx.x;         // 528 = 66 pos x 8 chunks
    const int pos = unit >> 3, chunk = unit & 7;
    const int oh = pos / 6, ow = pos % 6;
    const int tid = threadIdx.x, lane = tid & 63;

    if (tid < 128) {
        const float* src = lw2 + tid * 264 + pos * 4;
        int o = tid >> 4, c = tid & 15;
        #pragma unroll
        for (int k = 0; k < 4; k++) wld[c * 32 + k * 8 + o] = src[k];
    }
    if (tid < 16) {
        float m = aload(&stats[tid]) * (1.0f / 409600.0f);
        float v = aload(&stats[16 + tid]) * (1.0f / 409600.0f) - m * m;
        float a = g1[tid] * rsqrtf(v + 1e-5f);
        a1[tid] = a; b1[tid] = be1[tid] - a * m;
        if (tid < 8) bl[tid] = lb2[tid * 66 + pos];
        red[tid] = 0.0f;
    }
    __syncthreads();

    int base[4]; float kmv[4];
    #pragma unroll
    for (int i = 0; i < 2; i++)
        #pragma unroll
        for (int j = 0; j < 2; j++) {
            int r = oh + i - 1, c2 = ow + j - 1;
            bool ok = (r >= 0 && r < 10 && c2 >= 0 && c2 < 5);
            int rc = min(max(r, 0), 9), cc2 = min(max(c2, 0), 4);
            base[i * 2 + j] = rc * 5 + cc2;
            kmv[i * 2 + j] = ok ? 1.0f : 0.0f;
        }

    const int sb = chunk * 1024 + tid * 4;
    float acc[8][4];
    #pragma unroll
    for (int o = 0; o < 8; o++)
        #pragma unroll
        for (int s = 0; s < 4; s++) acc[o][s] = bl[o];

    #pragma unroll 1
    for (int c = 0; c < 16; c++) {
        float av = a1[c], bv = b1[c];
        float p[4][4];
        #pragma unroll
        for (int t = 0; t < 4; t++) {
            float ap = av * kmv[t], bp = bv * kmv[t];
            uint2 U = *(const uint2*)(y1b + (size_t)(c * 50 + base[t]) * 8192 + sb);
            p[t][0] = fmaf(ap, ubf(U.x & 0xffffu), bp);
            p[t][1] = fmaf(ap, __uint_as_float(U.x & 0xffff0000u), bp);
            p[t][2] = fmaf(ap, ubf(U.y & 0xffffu), bp);
            p[t][3] = fmaf(ap, __uint_as_float(U.y & 0xffff0000u), bp);
        }
        const float4* wr = (const float4*)&wld[c * 32];
        #pragma unroll
        for (int t = 0; t < 4; t++) {
            float4 wa = wr[t * 2], wb = wr[t * 2 + 1];
            #pragma unroll
            for (int s = 0; s < 4; s++) {
                float pv = p[t][s];
                acc[0][s] += wa.x * pv; acc[1][s] += wa.y * pv;
                acc[2][s] += wa.z * pv; acc[3][s] += wa.w * pv;
                acc[4][s] += wb.x * pv; acc[5][s] += wb.y * pv;
                acc[6][s] += wb.z * pv; acc[7][s] += wb.w * pv;
            }
        }
    }

    #pragma unroll
    for (int o = 0; o < 8; o++) {
        float v0 = LRELU(acc[o][0]), v1 = LRELU(acc[o][1]);
        float v2 = LRELU(acc[o][2]), v3 = LRELU(acc[o][3]);
        uint2 st = { bfr(v0) | (bfr(v1) << 16), bfr(v2) | (bfr(v3) << 16) };
        *(uint2*)(y2b + (size_t)(o * 66 + pos) * 8192 + sb) = st;
        float sv = v0 + v1 + v2 + v3;
        float sqv = v0 * v0 + v1 * v1 + v2 * v2 + v3 * v3;
        #pragma unroll
        for (int m = 32; m > 0; m >>= 1) {
            sv  += __shfl_xor(sv, m, 64);
            sqv += __shfl_xor(sqv, m, 64);
        }
        if (lane == 0) { atomicAdd(&red[o], sv); atomicAdd(&red[8 + o], sqv); }
    }
    __syncthreads();
    if (tid < 16) atomicAdd(&stats[32 + tid], red[tid]);
}

// ---------------- k3: lc3 ----------------
__global__ __launch_bounds__(256) void k3_lc3(
    const unsigned short* __restrict__ y2b,
    const float* __restrict__ lw3, const float* __restrict__ lb3,
    const float* __restrict__ g2, const float* __restrict__ be2,
    unsigned short* __restrict__ y3b, float* __restrict__ stats)
{
    __shared__ float wld[256];
    __shared__ float a2[8], b2[8], bl[8], red[16];

    const int unit = blockIdx.x;         // 384 = 48 pos x 8 chunks
    const int pos = unit >> 3, chunk = unit & 7;
    const int oh = pos >> 2, ow = pos & 3;
    const int tid = threadIdx.x, lane = tid & 63;

    if (tid < 64) {
        const float* src = lw3 + tid * 192 + pos * 4;
        int o = tid >> 3, c = tid & 7;
        #pragma unroll
        for (int k = 0; k < 4; k++) wld[c * 32 + k * 8 + o] = src[k];
    }
    if (tid < 16) {
        if (tid < 8) {
            float m = aload(&stats[32 + tid]) * (1.0f / 540672.0f);
            float v = aload(&stats[40 + tid]) * (1.0f / 540672.0f) - m * m;
            float a = g2[tid] * rsqrtf(v + 1e-5f);
            a2[tid] = a; b2[tid] = be2[tid] - a * m;
            bl[tid] = lb3[tid * 48 + pos];
        }
        red[tid] = 0.0f;
    }
    __syncthreads();

    int base[4]; float kmv[4];
    #pragma unroll
    for (int i = 0; i < 2; i++)
        #pragma unroll
        for (int j = 0; j < 2; j++) {
            int r = oh + i - 1, c2 = 2 * ow + j - 1;
            bool ok = (r >= 0 && r < 11 && c2 >= 0 && c2 < 6);
            int rc = min(max(r, 0), 10), cc2 = min(max(c2, 0), 5);
            base[i * 2 + j] = rc * 6 + cc2;
            kmv[i * 2 + j] = ok ? 1.0f : 0.0f;
        }

    const int sb = chunk * 1024 + tid * 4;
    float acc[8][4];
    #pragma unroll
    for (int o = 0; o < 8; o++)
        #pragma unroll
        for (int s = 0; s < 4; s++) acc[o][s] = bl[o];

    #pragma unroll 1
    for (int c = 0; c < 8; c++) {
        float av = a2[c], bv = b2[c];
        float p[4][4];
        #pragma unroll
        for (int t = 0; t < 4; t++) {
            float ap = av * kmv[t], bp = bv * kmv[t];
            uint2 U = *(const uint2*)(y2b + (size_t)(c * 66 + base[t]) * 8192 + sb);
            p[t][0] = fmaf(ap, ubf(U.x & 0xffffu), bp);
            p[t][1] = fmaf(ap, __uint_as_float(U.x & 0xffff0000u), bp);
            p[t][2] = fmaf(ap, ubf(U.y & 0xffffu), bp);
            p[t][3] = fmaf(ap, __uint_as_float(U.y & 0xffff0000u), bp);
        }
        const float4* wr = (const float4*)&wld[c * 32];
        #pragma unroll
        for (int t = 0; t < 4; t++) {
            float4 wa = wr[t * 2], wb = wr[t * 2 + 1];
            #pragma unroll
            for (int s = 0; s < 4; s++) {
                float pv = p[t][s];
                acc[0][s] += wa.x * pv; acc[1][s] += wa.y * pv;
                acc[2][s] += wa.z * pv; acc[3][s] += wa.w * pv;
                acc[4][s] += wb.x * pv; acc[5][s] += wb.y * pv;
                acc[6][s] += wb.z * pv; acc[7][s] += wb.w * pv;
            }
        }
    }

    #pragma unroll
    for (int o = 0; o < 8; o++) {
        float v0 = LRELU(acc[o][0]), v1 = LRELU(acc[o][1]);
        float v2 = LRELU(acc[o][2]), v3 = LRELU(acc[o][3]);
        uint2 st = { bfr(v0) | (bfr(v1) << 16), bfr(v2) | (bfr(v3) << 16) };
        *(uint2*)(y3b + (size_t)(o * 48 + pos) * 8192 + sb) = st;
        float sv = v0 + v1 + v2 + v3;
        float sqv = v0 * v0 + v1 * v1 + v2 * v2 + v3 * v3;
        #pragma unroll
        for (int m = 32; m > 0; m >>= 1) {
            sv  += __shfl_xor(sv, m, 64);
            sqv += __shfl_xor(sqv, m, 64);
        }
        if (lane == 0) { atomicAdd(&red[o], sv); atomicAdd(&red[8 + o], sqv); }
    }
    __syncthreads();
    if (tid < 16) atomicAdd(&stats[48 + tid], red[tid]);
}

// ---------------- k4: BN3 + transpose ----------------
__global__ __launch_bounds__(256) void k4_out(
    const unsigned short* __restrict__ y3b,
    const float* __restrict__ g3, const float* __restrict__ be3,
    float* __restrict__ stats, float* __restrict__ out)
{
    __shared__ unsigned short tile[64][66];
    __shared__ float a3[8], b3[8];
    const int unit = blockIdx.x;         // 768 = 24 (6 ftiles x 4 sub) x 32 chunks
    const int tid = threadIdx.x;
    const int chunkS = unit & 31, yy = unit >> 5;
    const int ftile = yy >> 2, sub = yy & 3;
    const int fbase = ftile * 64;
    const int sbase = chunkS * 256 + sub * 64;

    if (tid < 8) {
        float m = aload(&stats[48 + tid]) * (1.0f / 393216.0f);
        float v = aload(&stats[56 + tid]) * (1.0f / 393216.0f) - m * m;
        float a = g3[tid] * rsqrtf(v + 1e-5f);
        a3[tid] = a; b3[tid] = be3[tid] - a * m;
    }
    __syncthreads();

    #pragma unroll
    for (int rep = 0; rep < 16; rep++) {
        int idx = rep * 256 + tid;
        int f = idx >> 6, s = idx & 63;
        tile[f][s] = y3b[(size_t)(fbase + f) * 8192 + sbase + s];
    }
    __syncthreads();
    #pragma unroll
    for (int rep = 0; rep < 16; rep++) {
        int idx = rep * 256 + tid;
        int s = idx >> 6, f = idx & 63;
        int ff = fbase + f;
        int o = ff / 48;
        float x = ubf((unsigned)tile[f][s]);
        out[(size_t)(sbase + s) * 384 + ff] = a3[o] * x + b3[o];
    }
}

extern "C" void kernel_launch(void* const* d_in, const int* in_sizes, int n_in,
                              void* d_out, int out_size, void* d_ws, size_t ws_size,
                              hipStream_t stream) {
    const float* image   = (const float*)d_in[0];
    const float* conv1_w = (const float*)d_in[1];
    const float* conv1_b = (const float*)d_in[2];
    const float* lc1_w   = (const float*)d_in[3];
    const float* lc1_b   = (const float*)d_in[4];
    const float* lc2_w   = (const float*)d_in[5];
    const float* lc2_b   = (const float*)d_in[6];
    const float* lc3_w   = (const float*)d_in[7];
    const float* lc3_b   = (const float*)d_in[8];
    const float* gamma1  = (const float*)d_in[9];
    const float* beta1   = (const float*)d_in[10];
    const float* gamma2  = (const float*)d_in[11];
    const float* beta2   = (const float*)d_in[12];
    const float* gamma3  = (const float*)d_in[13];
    const float* beta3   = (const float*)d_in[14];
    float* outp = (float*)d_out;

    char* wsb = (char*)d_ws;
    float*          stats = (float*)wsb;                       // 1024 B
    unsigned short* y1b   = (unsigned short*)(wsb + 1024);     // 13,107,200 B
    int4*           afg1  = (int4*)(wsb + 13108224);           // 921,600 B
    char*           x1reg = wsb + 14029824;                    // x1 region (aliases y2b/y3b)
    unsigned short* y2b   = (unsigned short*)(wsb + 14029824); // 8,650,752 B (x1 dead by k2)
    unsigned short* y3b   = (unsigned short*)(wsb + 22680576); // 6,291,456 B

    // choose sample passes so x1 (11,520 B/sample) fits in ws
    const size_t bytesPerSamp = 11520;
    int nPass = 1;
    if (ws_size < 14029824ul + 8192ul * bytesPerSamp) nPass = 2;
    if (ws_size < 14029824ul + 4096ul * bytesPerSamp) nPass = 4;
    if (ws_size < 14029824ul + 2048ul * bytesPerSamp) nPass = 8;
    const int spp = 8192 / nPass;
    const int nA  = spp / 16;

    unsigned*   x1u = (unsigned*)x1reg;
    const int4* x1v = (const int4*)x1reg;

    for (int p = 0; p < nPass; ++p) {
        const float* imgp = image + (size_t)p * spp * 90;
        kprep<<<dim3(p == 0 ? nA + 51 : nA), dim3(256), 0, stream>>>(
            imgp, conv1_w, conv1_b, lc1_w, x1u, afg1, stats, nA, p == 0 ? 1 : 0);
        k1_lc1<<<dim3(spp / 256, 50), dim3(256), 0, stream>>>(
            x1v, afg1, lc1_b, y1b, stats, p * spp);
    }
    k2_lc2<<<dim3(528), dim3(256), 0, stream>>>(y1b, lc2_w, lc2_b,
                                                gamma1, beta1, y2b, stats);
    k3_lc3<<<dim3(384), dim3(256), 0, stream>>>(y2b, lc3_w, lc3_b,
                                                gamma2, beta2, y3b, stats);
    k4_out<<<dim3(768), dim3(256), 0, stream>>>(y3b, gamma3, beta3, stats, outp);
}

// Round 8
// 202.976 us; speedup vs baseline: 1.0891x; 1.0891x over previous
//
#include <hip/hip_runtime.h>

// Discriminator pipeline, R8.
// R7 post-mortem: hoisting conv1 fixed the VALU wall but k1 became
// memory-bound (FETCH 211MB, scattered 64B segments, L2 thrash).
// R8 fixes: (1) x1 layout [(hw,h) slab][samp][ch32] -> one B-frag load =
// 16 consecutive samples x 64B = 1KB fully dense; (2) k1 block swizzle
// id = k + 8*(pos + 50*gg), chunk = 8*gg + k -> each XCD sweeps all 50
// positions of ONE 2.95MB chunk slab (fits 4MB L2) before the next.
//  kprep: conv1+lrelu -> x1 bf16 slabs; pass0 also lc1 A-frags + zero stats.
//  k1  : lc1 pure-load MFMA GEMM -> y1b bf16 + BN1 stats.
//  k2  : lc2 VALU fp32, BN1 folded on bf16 uint2 loads -> y2b + BN2.
//  k3  : lc3 same -> y3b + BN3.
//  k4  : BN3 + bf16 LDS transpose -> out[8192][384] f32.

typedef float  f32x4 __attribute__((ext_vector_type(4)));
typedef float  f32x2 __attribute__((ext_vector_type(2)));
typedef short  bf16x8 __attribute__((ext_vector_type(8)));

union FR  { int4 i4; bf16x8 bf; unsigned u[4]; };

#define LRELU(v) fmaxf((v), 0.01f * (v))

static __device__ inline unsigned bfr(float f) {              // RNE fp32->bf16
    unsigned u = __float_as_uint(f);
    return (u + 0x7fffu + ((u >> 16) & 1u)) >> 16;
}
static __device__ inline unsigned short bfr16(float f) { return (unsigned short)bfr(f); }
static __device__ inline float ubf(unsigned lo16) { return __uint_as_float(lo16 << 16); }

#if __has_builtin(__builtin_elementwise_fma)
static __device__ inline f32x2 pk_fma(f32x2 a, f32x2 b, f32x2 c) { return __builtin_elementwise_fma(a, b, c); }
#else
static __device__ inline f32x2 pk_fma(f32x2 a, f32x2 b, f32x2 c) { return a * b + c; }
#endif
static __device__ inline f32x2 pk_lrelu(f32x2 v) {
#if __has_builtin(__builtin_elementwise_max)
    return __builtin_elementwise_max(v, v * 0.01f);
#else
    f32x2 r; r.x = LRELU(v.x); r.y = LRELU(v.y); return r;
#endif
}
static __device__ inline float aload(float* p) {
    return __hip_atomic_load(p, __ATOMIC_RELAXED, __HIP_MEMORY_SCOPE_AGENT);
}

// ---------------- kprep: conv1 -> x1 bf16 slabs (+ afg + stats on pass 0) --------
// x1 (u32 units): x1u[((hw*2 + h)*spp + sampLocal)*16 + chpos], packs ch {2chp,2chp+1}
union PrepSM { float imgP[16][110]; float wt[9216]; };   // 36 KB

__global__ __launch_bounds__(256) void kprep(
    const float* __restrict__ imgp,  // image + pass offset*90
    const float* __restrict__ cw,    // conv1_w [64*4]
    const float* __restrict__ cb,    // conv1_b [64]
    const float* __restrict__ lw1,   // lc1_w [16][64][450]
    unsigned* __restrict__ x1u,
    int4* __restrict__ afg1, float* __restrict__ stats,
    int nA, int doAux, int spp)
{
    __shared__ PrepSM sm;
    const int bx = blockIdx.x, tid = threadIdx.x;

    if (bx < nA) {
        const int sb = bx * 16;                      // local sample base (16 samples)
        for (int e = tid; e < 1760; e += 256) ((float*)sm.imgP)[e] = 0.0f;
        __syncthreads();
        for (int e = tid; e < 1440; e += 256) {
            int s = e / 90, hw = e - s * 90;
            int r = hw / 9, c = hw - r * 9;
            sm.imgP[s][r * 10 + c] = imgp[(size_t)sb * 90 + e];
        }
        __syncthreads();

        const int chp = tid & 31, sidx = tid >> 5;
        const int ch0 = 2 * chp;
        const int h = chp >> 4, chpos = chp & 15;
        f32x2 w00 = {cw[ch0 * 4 + 0], cw[ch0 * 4 + 4]};
        f32x2 w01 = {cw[ch0 * 4 + 1], cw[ch0 * 4 + 5]};
        f32x2 w10 = {cw[ch0 * 4 + 2], cw[ch0 * 4 + 6]};
        f32x2 w11 = {cw[ch0 * 4 + 3], cw[ch0 * 4 + 7]};
        f32x2 bb  = {cb[ch0], cb[ch0 + 1]};

        #pragma unroll
        for (int ss = 0; ss < 2; ++ss) {
            const int s = sidx + 8 * ss;
            const float* ip = sm.imgP[s];
            unsigned* dst = x1u + ((size_t)h * spp + (sb + s)) * 16 + chpos;
            #pragma unroll 2
            for (int r = 0; r < 10; ++r) {
                #pragma unroll
                for (int c = 0; c < 9; ++c) {
                    f32x2 v = bb;
                    v = pk_fma((f32x2)ip[r * 10 + c],      w00, v);
                    v = pk_fma((f32x2)ip[r * 10 + c + 1],  w01, v);
                    v = pk_fma((f32x2)ip[r * 10 + c + 10], w10, v);
                    v = pk_fma((f32x2)ip[r * 10 + c + 11], w11, v);
                    v = pk_lrelu(v);
                    dst[(size_t)(r * 9 + c) * 2 * spp * 16] = bfr(v.x) | (bfr(v.y) << 16);
                }
            }
        }
        return;
    }
    if (!doAux) return;

    const int b2 = bx - nA;
    if (b2 < 50) {                                   // lc1 A-fragments
        const int pos = b2;
        for (int e = tid; e < 9216; e += 256) {
            int pair = e / 9, t = e - 9 * pair;
            sm.wt[e] = lw1[pair * 450 + pos * 9 + t];
        }
        __syncthreads();
        for (int e = tid; e < 1152; e += 256) {
            int l = e & 63, ht = e >> 6;
            int h = (ht >= 9) ? 1 : 0, t = ht - 9 * h;
            int q = l >> 4, o = l & 15;
            unsigned uu[4];
            #pragma unroll
            for (int p = 0; p < 4; ++p) {
                int c0 = 32 * h + 8 * q + 2 * p;
                float a0 = sm.wt[(o * 64 + c0) * 9 + t];
                float a1 = sm.wt[(o * 64 + c0 + 1) * 9 + t];
                uu[p] = bfr(a0) | (bfr(a1) << 16);
            }
            int4 st = { (int)uu[0], (int)uu[1], (int)uu[2], (int)uu[3] };
            afg1[pos * 1152 + e] = st;
        }
    } else if (tid < 64) stats[tid] = 0.0f;
}

// ---------------- k1: lc1 pure-load MFMA GEMM ----------------
__global__ __launch_bounds__(256) void k1_lc1(
    const int4* __restrict__ x1v,    // slab layout, int4 units
    const int4* __restrict__ afg,    // lc1 A-frags
    const float* __restrict__ lb,    // lc1_b [16*50]
    unsigned short* __restrict__ y1b,// bf16 [800][8192]
    float* __restrict__ stats,       // [0..31] sum16/sq16
    int sampOff, int spp, int nc)    // pass offset, samples/pass, chunks/pass
{
    __shared__ int4  AfL[1152];      // 18432 B
    __shared__ float bl[16];
    __shared__ float red[32];

    int pos, chunk;
    {
        int id = blockIdx.x;
        if (nc >= 8) { int k8 = id & 7; int r = id >> 3; pos = r % 50; chunk = (r / 50) * 8 + k8; }
        else         { pos = id % 50; chunk = id / 50; }
    }
    const int oh = pos / 5, ow = pos % 5;
    const int tid = threadIdx.x;
    const int wv = tid >> 6, lane = tid & 63;
    const int lane15 = lane & 15, q = lane >> 4;

    for (int e = tid; e < 1152; e += 256) AfL[e] = afg[pos * 1152 + e];
    if (tid < 16) bl[tid] = lb[tid * 50 + pos];
    if (tid < 32) red[tid] = 0.0f;
    __syncthreads();

    const int sLoc = chunk * 256 + wv * 64;          // local (this pass)
    const int sAbs = sampOff + sLoc;                 // absolute (for y1b/stats)
    const int spp4 = spp * 4;                        // int4 per slab

    int base_g[4];
    #pragma unroll
    for (int g = 0; g < 4; ++g)
        base_g[g] = (sLoc + g * 16 + lane15) * 4 + q;

    f32x4 acc[4];
    #pragma unroll
    for (int g = 0; g < 4; ++g) acc[g] = (f32x4){0.f, 0.f, 0.f, 0.f};

    #pragma unroll
    for (int t = 0; t < 9; ++t) {
        const int ti = t / 3, tj = t % 3;
        const int r = oh + ti - 1, c2 = 2 * ow + tj - 1;
        if (r >= 0 && r < 10 && c2 >= 0 && c2 < 9) {         // block-uniform
            const int hw = r * 9 + c2;
            #pragma unroll
            for (int h = 0; h < 2; ++h) {
                FR fa; fa.i4 = AfL[(h * 9 + t) * 64 + lane];
                const int slabBase = (hw * 2 + h) * spp4;
                #pragma unroll
                for (int g = 0; g < 4; ++g) {
                    FR fb; fb.i4 = x1v[slabBase + base_g[g]];
                    acc[g] = __builtin_amdgcn_mfma_f32_16x16x32_bf16(fa.bf, fb.bf, acc[g], 0, 0, 0);
                }
            }
        }
    }

    float so[4] = {0, 0, 0, 0}, sq[4] = {0, 0, 0, 0};
    #pragma unroll
    for (int g = 0; g < 4; ++g)
        #pragma unroll
        for (int r = 0; r < 4; ++r) {
            int o = q * 4 + r;
            float v = acc[g][r] + bl[o];
            v = LRELU(v);
            y1b[(size_t)(o * 50 + pos) * 8192 + sAbs + g * 16 + lane15] = bfr16(v);
            so[r] += v; sq[r] += v * v;
        }
    #pragma unroll
    for (int r = 0; r < 4; ++r) {
        #pragma unroll
        for (int m = 1; m < 16; m <<= 1) {
            so[r] += __shfl_xor(so[r], m, 16);
            sq[r] += __shfl_xor(sq[r], m, 16);
        }
        if (lane15 == 0) {
            int o = q * 4 + r;
            atomicAdd(&red[o], so[r]);
            atomicAdd(&red[16 + o], sq[r]);
        }
    }
    __syncthreads();
    if (tid < 32) atomicAdd(&stats[tid], red[tid]);
}

// ---------------- k2: lc2 (VALU fp32, bf16 uint2 IO) ----------------
__global__ __launch_bounds__(256) void k2_lc2(
    const unsigned short* __restrict__ y1b,
    const float* __restrict__ lw2, const float* __restrict__ lb2,
    const float* __restrict__ g1, const float* __restrict__ be1,
    unsigned short* __restrict__ y2b, float* __restrict__ stats)
{
    __shared__ float wld[512];
    __shared__ float a1[16], b1[16], bl[8], red[16];

    const int unit = blockIdx.x;         // 528 = 66 pos x 8 chunks
    const int pos = unit >> 3, chunk = unit & 7;
    const int oh = pos / 6, ow = pos % 6;
    const int tid = threadIdx.x, lane = tid & 63;

    if (tid < 128) {
        const float* src = lw2 + tid * 264 + pos * 4;
        int o = tid >> 4, c = tid & 15;
        #pragma unroll
        for (int k = 0; k < 4; k++) wld[c * 32 + k * 8 + o] = src[k];
    }
    if (tid < 16) {
        float m = aload(&stats[tid]) * (1.0f / 409600.0f);
        float v = aload(&stats[16 + tid]) * (1.0f / 409600.0f) - m * m;
        float a = g1[tid] * rsqrtf(v + 1e-5f);
        a1[tid] = a; b1[tid] = be1[tid] - a * m;
        if (tid < 8) bl[tid] = lb2[tid * 66 + pos];
        red[tid] = 0.0f;
    }
    __syncthreads();

    int base[4]; float kmv[4];
    #pragma unroll
    for (int i = 0; i < 2; i++)
        #pragma unroll
        for (int j = 0; j < 2; j++) {
            int r = oh + i - 1, c2 = ow + j - 1;
            bool ok = (r >= 0 && r < 10 && c2 >= 0 && c2 < 5);
            int rc = min(max(r, 0), 9), cc2 = min(max(c2, 0), 4);
            base[i * 2 + j] = rc * 5 + cc2;
            kmv[i * 2 + j] = ok ? 1.0f : 0.0f;
        }

    const int sb = chunk * 1024 + tid * 4;
    float acc[8][4];
    #pragma unroll
    for (int o = 0; o < 8; o++)
        #pragma unroll
        for (int s = 0; s < 4; s++) acc[o][s] = bl[o];

    #pragma unroll 1
    for (int c = 0; c < 16; c++) {
        float av = a1[c], bv = b1[c];
        float p[4][4];
        #pragma unroll
        for (int t = 0; t < 4; t++) {
            float ap = av * kmv[t], bp = bv * kmv[t];
            uint2 U = *(const uint2*)(y1b + (size_t)(c * 50 + base[t]) * 8192 + sb);
            p[t][0] = fmaf(ap, ubf(U.x & 0xffffu), bp);
            p[t][1] = fmaf(ap, __uint_as_float(U.x & 0xffff0000u), bp);
            p[t][2] = fmaf(ap, ubf(U.y & 0xffffu), bp);
            p[t][3] = fmaf(ap, __uint_as_float(U.y & 0xffff0000u), bp);
        }
        const float4* wr = (const float4*)&wld[c * 32];
        #pragma unroll
        for (int t = 0; t < 4; t++) {
            float4 wa = wr[t * 2], wb = wr[t * 2 + 1];
            #pragma unroll
            for (int s = 0; s < 4; s++) {
                float pv = p[t][s];
                acc[0][s] += wa.x * pv; acc[1][s] += wa.y * pv;
                acc[2][s] += wa.z * pv; acc[3][s] += wa.w * pv;
                acc[4][s] += wb.x * pv; acc[5][s] += wb.y * pv;
                acc[6][s] += wb.z * pv; acc[7][s] += wb.w * pv;
            }
        }
    }

    #pragma unroll
    for (int o = 0; o < 8; o++) {
        float v0 = LRELU(acc[o][0]), v1 = LRELU(acc[o][1]);
        float v2 = LRELU(acc[o][2]), v3 = LRELU(acc[o][3]);
        uint2 st = { bfr(v0) | (bfr(v1) << 16), bfr(v2) | (bfr(v3) << 16) };
        *(uint2*)(y2b + (size_t)(o * 66 + pos) * 8192 + sb) = st;
        float sv = v0 + v1 + v2 + v3;
        float sqv = v0 * v0 + v1 * v1 + v2 * v2 + v3 * v3;
        #pragma unroll
        for (int m = 32; m > 0; m >>= 1) {
            sv  += __shfl_xor(sv, m, 64);
            sqv += __shfl_xor(sqv, m, 64);
        }
        if (lane == 0) { atomicAdd(&red[o], sv); atomicAdd(&red[8 + o], sqv); }
    }
    __syncthreads();
    if (tid < 16) atomicAdd(&stats[32 + tid], red[tid]);
}

// ---------------- k3: lc3 ----------------
__global__ __launch_bounds__(256) void k3_lc3(
    const unsigned short* __restrict__ y2b,
    const float* __restrict__ lw3, const float* __restrict__ lb3,
    const float* __restrict__ g2, const float* __restrict__ be2,
    unsigned short* __restrict__ y3b, float* __restrict__ stats)
{
    __shared__ float wld[256];
    __shared__ float a2[8], b2[8], bl[8], red[16];

    const int unit = blockIdx.x;         // 384 = 48 pos x 8 chunks
    const int pos = unit >> 3, chunk = unit & 7;
    const int oh = pos >> 2, ow = pos & 3;
    const int tid = threadIdx.x, lane = tid & 63;

    if (tid < 64) {
        const float* src = lw3 + tid * 192 + pos * 4;
        int o = tid >> 3, c = tid & 7;
        #pragma unroll
        for (int k = 0; k < 4; k++) wld[c * 32 + k * 8 + o] = src[k];
    }
    if (tid < 16) {
        if (tid < 8) {
            float m = aload(&stats[32 + tid]) * (1.0f / 540672.0f);
            float v = aload(&stats[40 + tid]) * (1.0f / 540672.0f) - m * m;
            float a = g2[tid] * rsqrtf(v + 1e-5f);
            a2[tid] = a; b2[tid] = be2[tid] - a * m;
            bl[tid] = lb3[tid * 48 + pos];
        }
        red[tid] = 0.0f;
    }
    __syncthreads();

    int base[4]; float kmv[4];
    #pragma unroll
    for (int i = 0; i < 2; i++)
        #pragma unroll
        for (int j = 0; j < 2; j++) {
            int r = oh + i - 1, c2 = 2 * ow + j - 1;
            bool ok = (r >= 0 && r < 11 && c2 >= 0 && c2 < 6);
            int rc = min(max(r, 0), 10), cc2 = min(max(c2, 0), 5);
            base[i * 2 + j] = rc * 6 + cc2;
            kmv[i * 2 + j] = ok ? 1.0f : 0.0f;
        }

    const int sb = chunk * 1024 + tid * 4;
    float acc[8][4];
    #pragma unroll
    for (int o = 0; o < 8; o++)
        #pragma unroll
        for (int s = 0; s < 4; s++) acc[o][s] = bl[o];

    #pragma unroll 1
    for (int c = 0; c < 8; c++) {
        float av = a2[c], bv = b2[c];
        float p[4][4];
        #pragma unroll
        for (int t = 0; t < 4; t++) {
            float ap = av * kmv[t], bp = bv * kmv[t];
            uint2 U = *(const uint2*)(y2b + (size_t)(c * 66 + base[t]) * 8192 + sb);
            p[t][0] = fmaf(ap, ubf(U.x & 0xffffu), bp);
            p[t][1] = fmaf(ap, __uint_as_float(U.x & 0xffff0000u), bp);
            p[t][2] = fmaf(ap, ubf(U.y & 0xffffu), bp);
            p[t][3] = fmaf(ap, __uint_as_float(U.y & 0xffff0000u), bp);
        }
        const float4* wr = (const float4*)&wld[c * 32];
        #pragma unroll
        for (int t = 0; t < 4; t++) {
            float4 wa = wr[t * 2], wb = wr[t * 2 + 1];
            #pragma unroll
            for (int s = 0; s < 4; s++) {
                float pv = p[t][s];
                acc[0][s] += wa.x * pv; acc[1][s] += wa.y * pv;
                acc[2][s] += wa.z * pv; acc[3][s] += wa.w * pv;
                acc[4][s] += wb.x * pv; acc[5][s] += wb.y * pv;
                acc[6][s] += wb.z * pv; acc[7][s] += wb.w * pv;
            }
        }
    }

    #pragma unroll
    for (int o = 0; o < 8; o++) {
        float v0 = LRELU(acc[o][0]), v1 = LRELU(acc[o][1]);
        float v2 = LRELU(acc[o][2]), v3 = LRELU(acc[o][3]);
        uint2 st = { bfr(v0) | (bfr(v1) << 16), bfr(v2) | (bfr(v3) << 16) };
        *(uint2*)(y3b + (size_t)(o * 48 + pos) * 8192 + sb) = st;
        float sv = v0 + v1 + v2 + v3;
        float sqv = v0 * v0 + v1 * v1 + v2 * v2 + v3 * v3;
        #pragma unroll
        for (int m = 32; m > 0; m >>= 1) {
            sv  += __shfl_xor(sv, m, 64);
            sqv += __shfl_xor(sqv, m, 64);
        }
        if (lane == 0) { atomicAdd(&red[o], sv); atomicAdd(&red[8 + o], sqv); }
    }
    __syncthreads();
    if (tid < 16) atomicAdd(&stats[48 + tid], red[tid]);
}

// ---------------- k4: BN3 + transpose ----------------
__global__ __launch_bounds__(256) void k4_out(
    const unsigned short* __restrict__ y3b,
    const float* __restrict__ g3, const float* __restrict__ be3,
    float* __restrict__ stats, float* __restrict__ out)
{
    __shared__ unsigned short tile[64][66];
    __shared__ float a3[8], b3[8];
    const int unit = blockIdx.x;         // 768 = 24 (6 ftiles x 4 sub) x 32 chunks
    const int tid = threadIdx.x;
    const int chunkS = unit & 31, yy = unit >> 5;
    const int ftile = yy >> 2, sub = yy & 3;
    const int fbase = ftile * 64;
    const int sbase = chunkS * 256 + sub * 64;

    if (tid < 8) {
        float m = aload(&stats[48 + tid]) * (1.0f / 393216.0f);
        float v = aload(&stats[56 + tid]) * (1.0f / 393216.0f) - m * m;
        float a = g3[tid] * rsqrtf(v + 1e-5f);
        a3[tid] = a; b3[tid] = be3[tid] - a * m;
    }
    __syncthreads();

    #pragma unroll
    for (int rep = 0; rep < 16; rep++) {
        int idx = rep * 256 + tid;
        int f = idx >> 6, s = idx & 63;
        tile[f][s] = y3b[(size_t)(fbase + f) * 8192 + sbase + s];
    }
    __syncthreads();
    #pragma unroll
    for (int rep = 0; rep < 16; rep++) {
        int idx = rep * 256 + tid;
        int s = idx >> 6, f = idx & 63;
        int ff = fbase + f;
        int o = ff / 48;
        float x = ubf((unsigned)tile[f][s]);
        out[(size_t)(sbase + s) * 384 + ff] = a3[o] * x + b3[o];
    }
}

extern "C" void kernel_launch(void* const* d_in, const int* in_sizes, int n_in,
                              void* d_out, int out_size, void* d_ws, size_t ws_size,
                              hipStream_t stream) {
    const float* image   = (const float*)d_in[0];
    const float* conv1_w = (const float*)d_in[1];
    const float* conv1_b = (const float*)d_in[2];
    const float* lc1_w   = (const float*)d_in[3];
    const float* lc1_b   = (const float*)d_in[4];
    const float* lc2_w   = (const float*)d_in[5];
    const float* lc2_b   = (const float*)d_in[6];
    const float* lc3_w   = (const float*)d_in[7];
    const float* lc3_b   = (const float*)d_in[8];
    const float* gamma1  = (const float*)d_in[9];
    const float* beta1   = (const float*)d_in[10];
    const float* gamma2  = (const float*)d_in[11];
    const float* beta2   = (const float*)d_in[12];
    const float* gamma3  = (const float*)d_in[13];
    const float* beta3   = (const float*)d_in[14];
    float* outp = (float*)d_out;

    char* wsb = (char*)d_ws;
    float*          stats = (float*)wsb;                       // 1024 B
    unsigned short* y1b   = (unsigned short*)(wsb + 1024);     // 13,107,200 B
    int4*           afg1  = (int4*)(wsb + 13108224);           // 921,600 B
    char*           x1reg = wsb + 14029824;                    // x1 region (aliases y2b/y3b)
    unsigned short* y2b   = (unsigned short*)(wsb + 14029824); // 8,650,752 B (x1 dead by k2)
    unsigned short* y3b   = (unsigned short*)(wsb + 22680576); // 6,291,456 B

    // choose sample passes so x1 (11,520 B/sample) fits in ws
    const size_t bytesPerSamp = 11520;
    int nPass = 1;
    if (ws_size < 14029824ul + 8192ul * bytesPerSamp) nPass = 2;
    if (ws_size < 14029824ul + 4096ul * bytesPerSamp) nPass = 4;
    if (ws_size < 14029824ul + 2048ul * bytesPerSamp) nPass = 8;
    const int spp = 8192 / nPass;
    const int nA  = spp / 16;
    const int nc  = spp / 256;

    unsigned*   x1u = (unsigned*)x1reg;
    const int4* x1v = (const int4*)x1reg;

    for (int p = 0; p < nPass; ++p) {
        const float* imgp = image + (size_t)p * spp * 90;
        kprep<<<dim3(p == 0 ? nA + 51 : nA), dim3(256), 0, stream>>>(
            imgp, conv1_w, conv1_b, lc1_w, x1u, afg1, stats, nA, p == 0 ? 1 : 0, spp);
        k1_lc1<<<dim3(50 * nc), dim3(256), 0, stream>>>(
            x1v, afg1, lc1_b, y1b, stats, p * spp, spp, nc);
    }
    k2_lc2<<<dim3(528), dim3(256), 0, stream>>>(y1b, lc2_w, lc2_b,
                                                gamma1, beta1, y2b, stats);
    k3_lc3<<<dim3(384), dim3(256), 0, stream>>>(y2b, lc3_w, lc3_b,
                                                gamma2, beta2, y3b, stats);
    k4_out<<<dim3(768), dim3(256), 0, stream>>>(y3b, gamma3, beta3, stats, outp);
}

// Round 9
// 193.696 us; speedup vs baseline: 1.1413x; 1.0479x over previous
//
#include <hip/hip_runtime.h>

// Discriminator pipeline, R9.
// R8 post-mortem: k1 latency-bound (VGPR=32 -> ~4 loads in flight, VALUBusy
// 10%, MfmaUtil 4%). R9: (1) k1 issues all 18 tap loads per sample-group into
// a register array BEFORE the 18 MFMAs (uniform unrolled loop; invalid taps
// use a zero A-frag block in LDS); (2) kprep writes uint4 (wave = 1KB dense).
//  kprep: conv1+lrelu -> x1 bf16 slabs [(hw,h)][samp][ch32]; pass0: A-frags+stats.
//  k1  : lc1 pure-load MFMA GEMM -> y1b bf16 + BN1 stats. XCD swizzle id%8.
//  k2  : lc2 VALU fp32, BN1 folded on bf16 uint2 loads -> y2b + BN2.
//  k3  : lc3 same -> y3b + BN3.
//  k4  : BN3 + bf16 LDS transpose -> out[8192][384] f32.

typedef float  f32x4 __attribute__((ext_vector_type(4)));
typedef float  f32x2 __attribute__((ext_vector_type(2)));
typedef short  bf16x8 __attribute__((ext_vector_type(8)));

union FR  { int4 i4; bf16x8 bf; unsigned u[4]; };

#define LRELU(v) fmaxf((v), 0.01f * (v))

static __device__ inline unsigned bfr(float f) {              // RNE fp32->bf16
    unsigned u = __float_as_uint(f);
    return (u + 0x7fffu + ((u >> 16) & 1u)) >> 16;
}
static __device__ inline unsigned short bfr16(float f) { return (unsigned short)bfr(f); }
static __device__ inline float ubf(unsigned lo16) { return __uint_as_float(lo16 << 16); }

#if __has_builtin(__builtin_elementwise_fma)
static __device__ inline f32x2 pk_fma(f32x2 a, f32x2 b, f32x2 c) { return __builtin_elementwise_fma(a, b, c); }
#else
static __device__ inline f32x2 pk_fma(f32x2 a, f32x2 b, f32x2 c) { return a * b + c; }
#endif
static __device__ inline f32x2 pk_lrelu(f32x2 v) {
#if __has_builtin(__builtin_elementwise_max)
    return __builtin_elementwise_max(v, v * 0.01f);
#else
    f32x2 r; r.x = LRELU(v.x); r.y = LRELU(v.y); return r;
#endif
}
static __device__ inline float aload(float* p) {
    return __hip_atomic_load(p, __ATOMIC_RELAXED, __HIP_MEMORY_SCOPE_AGENT);
}

// ---------------- kprep: conv1 -> x1 bf16 slabs (+ afg + stats on pass 0) --------
// x1 (u32 units): x1u[((hw*2 + h)*spp + sampLocal)*16 + chpos], packs ch {2chp,2chp+1}
union PrepSM { float imgP[16][110]; float wt[9216]; };   // 36 KB

__global__ __launch_bounds__(256) void kprep(
    const float* __restrict__ imgp,  // image + pass offset*90
    const float* __restrict__ cw,    // conv1_w [64*4]
    const float* __restrict__ cb,    // conv1_b [64]
    const float* __restrict__ lw1,   // lc1_w [16][64][450]
    unsigned* __restrict__ x1u,
    int4* __restrict__ afg1, float* __restrict__ stats,
    int nA, int doAux, int spp)
{
    __shared__ PrepSM sm;
    const int bx = blockIdx.x, tid = threadIdx.x;

    if (bx < nA) {
        const int sb = bx * 16;                      // local sample base (16 samples)
        for (int e = tid; e < 1760; e += 256) ((float*)sm.imgP)[e] = 0.0f;
        __syncthreads();
        for (int e = tid; e < 1440; e += 256) {
            int s = e / 90, hw = e - s * 90;
            int r = hw / 9, c = hw - r * 9;
            sm.imgP[s][r * 10 + c] = imgp[(size_t)sb * 90 + e];
        }
        __syncthreads();

        // thread -> (quad, samp, h, hw-pair): wave writes 64 consecutive uint4
        const int quad = tid & 3, s = (tid >> 2) & 15;
        const int h = (tid >> 6) & 1, hwo = tid >> 7;
        const int ch0 = h * 32 + quad * 8;           // this thread's 8 channels
        f32x2 W00[4], W01[4], W10[4], W11[4], BB[4];
        #pragma unroll
        for (int p = 0; p < 4; ++p) {
            int ca = ch0 + 2 * p, cbn = ca + 1;
            W00[p] = (f32x2){cw[ca * 4 + 0], cw[cbn * 4 + 0]};
            W01[p] = (f32x2){cw[ca * 4 + 1], cw[cbn * 4 + 1]};
            W10[p] = (f32x2){cw[ca * 4 + 2], cw[cbn * 4 + 2]};
            W11[p] = (f32x2){cw[ca * 4 + 3], cw[cbn * 4 + 3]};
            BB[p]  = (f32x2){cb[ca], cb[cbn]};
        }
        const float* ip = sm.imgP[s];
        uint4* x1q = (uint4*)x1u;
        #pragma unroll 3
        for (int it = 0; it < 45; ++it) {
            int hw = it * 2 + hwo;
            int r = hw / 9, c = hw - r * 9;
            float i00 = ip[r * 10 + c],      i01 = ip[r * 10 + c + 1];
            float i10 = ip[r * 10 + c + 10], i11 = ip[r * 10 + c + 11];
            unsigned u[4];
            #pragma unroll
            for (int p = 0; p < 4; ++p) {
                f32x2 v = BB[p];
                v = pk_fma((f32x2)i00, W00[p], v);
                v = pk_fma((f32x2)i01, W01[p], v);
                v = pk_fma((f32x2)i10, W10[p], v);
                v = pk_fma((f32x2)i11, W11[p], v);
                v = pk_lrelu(v);
                u[p] = bfr(v.x) | (bfr(v.y) << 16);
            }
            x1q[((size_t)(hw * 2 + h) * spp + (sb + s)) * 4 + quad] =
                make_uint4(u[0], u[1], u[2], u[3]);
        }
        return;
    }
    if (!doAux) return;

    const int b2 = bx - nA;
    if (b2 < 50) {                                   // lc1 A-fragments
        const int pos = b2;
        for (int e = tid; e < 9216; e += 256) {
            int pair = e / 9, t = e - 9 * pair;
            sm.wt[e] = lw1[pair * 450 + pos * 9 + t];
        }
        __syncthreads();
        for (int e = tid; e < 1152; e += 256) {
            int l = e & 63, ht = e >> 6;
            int h = (ht >= 9) ? 1 : 0, t = ht - 9 * h;
            int q = l >> 4, o = l & 15;
            unsigned uu[4];
            #pragma unroll
            for (int p = 0; p < 4; ++p) {
                int c0 = 32 * h + 8 * q + 2 * p;
                float a0 = sm.wt[(o * 64 + c0) * 9 + t];
                float a1 = sm.wt[(o * 64 + c0 + 1) * 9 + t];
                uu[p] = bfr(a0) | (bfr(a1) << 16);
            }
            int4 st = { (int)uu[0], (int)uu[1], (int)uu[2], (int)uu[3] };
            afg1[pos * 1152 + e] = st;
        }
    } else if (tid < 64) stats[tid] = 0.0f;
}

// ---------------- k1: lc1 pure-load MFMA GEMM, 18-deep load pipeline ----------
__global__ __launch_bounds__(256) void k1_lc1(
    const int4* __restrict__ x1v,    // slab layout, int4 units
    const int4* __restrict__ afg,    // lc1 A-frags
    const float* __restrict__ lb,    // lc1_b [16*50]
    unsigned short* __restrict__ y1b,// bf16 [800][8192]
    float* __restrict__ stats,       // [0..31] sum16/sq16
    int sampOff, int spp, int nc)
{
    __shared__ int4  AfL[1216];      // 1152 frags + 64-entry ZERO block @1152
    __shared__ float bl[16];
    __shared__ float red[32];

    int pos, chunk;
    {
        int id = blockIdx.x;
        if (nc >= 8) { int k8 = id & 7; int r = id >> 3; pos = r % 50; chunk = (r / 50) * 8 + k8; }
        else         { pos = id % 50; chunk = id / 50; }
    }
    const int oh = pos / 5, ow = pos % 5;
    const int tid = threadIdx.x;
    const int wv = tid >> 6, lane = tid & 63;
    const int lane15 = lane & 15, q = lane >> 4;

    for (int e = tid; e < 1152; e += 256) AfL[e] = afg[pos * 1152 + e];
    if (tid < 64) AfL[1152 + tid] = (int4){0, 0, 0, 0};
    if (tid < 16) bl[tid] = lb[tid * 50 + pos];
    if (tid < 32) red[tid] = 0.0f;
    __syncthreads();

    const int sLoc = chunk * 256 + wv * 64;
    const int sAbs = sampOff + sLoc;
    const int spp4 = spp * 4;

    // uniform tap tables: invalid tap -> clamp slab to hw=0, A-frag -> zero block
    int sb0[9], af0[9], af1[9];
    #pragma unroll
    for (int t = 0; t < 9; ++t) {
        int ti = t / 3, tj = t % 3;
        int r = oh + ti - 1, c2 = 2 * ow + tj - 1;
        bool ok = (r >= 0 && r < 10 && c2 >= 0 && c2 < 9);
        int hw = ok ? (r * 9 + c2) : 0;
        sb0[t] = hw * 2 * spp4;
        af0[t] = ok ? t * 64 : 1152;
        af1[t] = ok ? (9 + t) * 64 : 1152;
    }

    f32x4 acc[4];
    #pragma unroll
    for (int g = 0; g < 4; ++g) {
        const int bg = (sLoc + g * 16 + lane15) * 4 + q;
        FR fb[9][2];                       // all 18 loads issued before MFMAs
        #pragma unroll
        for (int t = 0; t < 9; ++t) {
            fb[t][0].i4 = x1v[sb0[t] + bg];
            fb[t][1].i4 = x1v[sb0[t] + spp4 + bg];
        }
        f32x4 a = (f32x4){0.f, 0.f, 0.f, 0.f};
        #pragma unroll
        for (int t = 0; t < 9; ++t) {
            FR fa0; fa0.i4 = AfL[af0[t] + lane];
            a = __builtin_amdgcn_mfma_f32_16x16x32_bf16(fa0.bf, fb[t][0].bf, a, 0, 0, 0);
            FR fa1; fa1.i4 = AfL[af1[t] + lane];
            a = __builtin_amdgcn_mfma_f32_16x16x32_bf16(fa1.bf, fb[t][1].bf, a, 0, 0, 0);
        }
        acc[g] = a;
    }

    float so[4] = {0, 0, 0, 0}, sq[4] = {0, 0, 0, 0};
    #pragma unroll
    for (int g = 0; g < 4; ++g)
        #pragma unroll
        for (int r = 0; r < 4; ++r) {
            int o = q * 4 + r;
            float v = acc[g][r] + bl[o];
            v = LRELU(v);
            y1b[(size_t)(o * 50 + pos) * 8192 + sAbs + g * 16 + lane15] = bfr16(v);
            so[r] += v; sq[r] += v * v;
        }
    #pragma unroll
    for (int r = 0; r < 4; ++r) {
        #pragma unroll
        for (int m = 1; m < 16; m <<= 1) {
            so[r] += __shfl_xor(so[r], m, 16);
            sq[r] += __shfl_xor(sq[r], m, 16);
        }
        if (lane15 == 0) {
            int o = q * 4 + r;
            atomicAdd(&red[o], so[r]);
            atomicAdd(&red[16 + o], sq[r]);
        }
    }
    __syncthreads();
    if (tid < 32) atomicAdd(&stats[tid], red[tid]);
}

// ---------------- k2: lc2 (VALU fp32, bf16 uint2 IO) ----------------
__global__ __launch_bounds__(256) void k2_lc2(
    const unsigned short* __restrict__ y1b,
    const float* __restrict__ lw2, const float* __restrict__ lb2,
    const float* __restrict__ g1, const float* __restrict__ be1,
    unsigned short* __restrict__ y2b, float* __restrict__ stats)
{
    __shared__ float wld[512];
    __shared__ float a1[16], b1[16], bl[8], red[16];

    const int unit = blockIdx.x;         // 528 = 66 pos x 8 chunks
    const int pos = unit >> 3, chunk = unit & 7;
    const int oh = pos / 6, ow = pos % 6;
    const int tid = threadIdx.x, lane = tid & 63;

    if (tid < 128) {
        const float* src = lw2 + tid * 264 + pos * 4;
        int o = tid >> 4, c = tid & 15;
        #pragma unroll
        for (int k = 0; k < 4; k++) wld[c * 32 + k * 8 + o] = src[k];
    }
    if (tid < 16) {
        float m = aload(&stats[tid]) * (1.0f / 409600.0f);
        float v = aload(&stats[16 + tid]) * (1.0f / 409600.0f) - m * m;
        float a = g1[tid] * rsqrtf(v + 1e-5f);
        a1[tid] = a; b1[tid] = be1[tid] - a * m;
        if (tid < 8) bl[tid] = lb2[tid * 66 + pos];
        red[tid] = 0.0f;
    }
    __syncthreads();

    int base[4]; float kmv[4];
    #pragma unroll
    for (int i = 0; i < 2; i++)
        #pragma unroll
        for (int j = 0; j < 2; j++) {
            int r = oh + i - 1, c2 = ow + j - 1;
            bool ok = (r >= 0 && r < 10 && c2 >= 0 && c2 < 5);
            int rc = min(max(r, 0), 9), cc2 = min(max(c2, 0), 4);
            base[i * 2 + j] = rc * 5 + cc2;
            kmv[i * 2 + j] = ok ? 1.0f : 0.0f;
        }

    const int sb = chunk * 1024 + tid * 4;
    float acc[8][4];
    #pragma unroll
    for (int o = 0; o < 8; o++)
        #pragma unroll
        for (int s = 0; s < 4; s++) acc[o][s] = bl[o];

    #pragma unroll 1
    for (int c = 0; c < 16; c++) {
        float av = a1[c], bv = b1[c];
        float p[4][4];
        #pragma unroll
        for (int t = 0; t < 4; t++) {
            float ap = av * kmv[t], bp = bv * kmv[t];
            uint2 U = *(const uint2*)(y1b + (size_t)(c * 50 + base[t]) * 8192 + sb);
            p[t][0] = fmaf(ap, ubf(U.x & 0xffffu), bp);
            p[t][1] = fmaf(ap, __uint_as_float(U.x & 0xffff0000u), bp);
            p[t][2] = fmaf(ap, ubf(U.y & 0xffffu), bp);
            p[t][3] = fmaf(ap, __uint_as_float(U.y & 0xffff0000u), bp);
        }
        const float4* wr = (const float4*)&wld[c * 32];
        #pragma unroll
        for (int t = 0; t < 4; t++) {
            float4 wa = wr[t * 2], wb = wr[t * 2 + 1];
            #pragma unroll
            for (int s = 0; s < 4; s++) {
                float pv = p[t][s];
                acc[0][s] += wa.x * pv; acc[1][s] += wa.y * pv;
                acc[2][s] += wa.z * pv; acc[3][s] += wa.w * pv;
                acc[4][s] += wb.x * pv; acc[5][s] += wb.y * pv;
                acc[6][s] += wb.z * pv; acc[7][s] += wb.w * pv;
            }
        }
    }

    #pragma unroll
    for (int o = 0; o < 8; o++) {
        float v0 = LRELU(acc[o][0]), v1 = LRELU(acc[o][1]);
        float v2 = LRELU(acc[o][2]), v3 = LRELU(acc[o][3]);
        uint2 st = { bfr(v0) | (bfr(v1) << 16), bfr(v2) | (bfr(v3) << 16) };
        *(uint2*)(y2b + (size_t)(o * 66 + pos) * 8192 + sb) = st;
        float sv = v0 + v1 + v2 + v3;
        float sqv = v0 * v0 + v1 * v1 + v2 * v2 + v3 * v3;
        #pragma unroll
        for (int m = 32; m > 0; m >>= 1) {
            sv  += __shfl_xor(sv, m, 64);
            sqv += __shfl_xor(sqv, m, 64);
        }
        if (lane == 0) { atomicAdd(&red[o], sv); atomicAdd(&red[8 + o], sqv); }
    }
    __syncthreads();
    if (tid < 16) atomicAdd(&stats[32 + tid], red[tid]);
}

// ---------------- k3: lc3 ----------------
__global__ __launch_bounds__(256) void k3_lc3(
    const unsigned short* __restrict__ y2b,
    const float* __restrict__ lw3, const float* __restrict__ lb3,
    const float* __restrict__ g2, const float* __restrict__ be2,
    unsigned short* __restrict__ y3b, float* __restrict__ stats)
{
    __shared__ float wld[256];
    __shared__ float a2[8], b2[8], bl[8], red[16];

    const int unit = blockIdx.x;         // 384 = 48 pos x 8 chunks
    const int pos = unit >> 3, chunk = unit & 7;
    const int oh = pos >> 2, ow = pos & 3;
    const int tid = threadIdx.x, lane = tid & 63;

    if (tid < 64) {
        const float* src = lw3 + tid * 192 + pos * 4;
        int o = tid >> 3, c = tid & 7;
        #pragma unroll
        for (int k = 0; k < 4; k++) wld[c * 32 + k * 8 + o] = src[k];
    }
    if (tid < 16) {
        if (tid < 8) {
            float m = aload(&stats[32 + tid]) * (1.0f / 540672.0f);
            float v = aload(&stats[40 + tid]) * (1.0f / 540672.0f) - m * m;
            float a = g2[tid] * rsqrtf(v + 1e-5f);
            a2[tid] = a; b2[tid] = be2[tid] - a * m;
            bl[tid] = lb3[tid * 48 + pos];
        }
        red[tid] = 0.0f;
    }
    __syncthreads();

    int base[4]; float kmv[4];
    #pragma unroll
    for (int i = 0; i < 2; i++)
        #pragma unroll
        for (int j = 0; j < 2; j++) {
            int r = oh + i - 1, c2 = 2 * ow + j - 1;
            bool ok = (r >= 0 && r < 11 && c2 >= 0 && c2 < 6);
            int rc = min(max(r, 0), 10), cc2 = min(max(c2, 0), 5);
            base[i * 2 + j] = rc * 6 + cc2;
            kmv[i * 2 + j] = ok ? 1.0f : 0.0f;
        }

    const int sb = chunk * 1024 + tid * 4;
    float acc[8][4];
    #pragma unroll
    for (int o = 0; o < 8; o++)
        #pragma unroll
        for (int s = 0; s < 4; s++) acc[o][s] = bl[o];

    #pragma unroll 1
    for (int c = 0; c < 8; c++) {
        float av = a2[c], bv = b2[c];
        float p[4][4];
        #pragma unroll
        for (int t = 0; t < 4; t++) {
            float ap = av * kmv[t], bp = bv * kmv[t];
            uint2 U = *(const uint2*)(y2b + (size_t)(c * 66 + base[t]) * 8192 + sb);
            p[t][0] = fmaf(ap, ubf(U.x & 0xffffu), bp);
            p[t][1] = fmaf(ap, __uint_as_float(U.x & 0xffff0000u), bp);
            p[t][2] = fmaf(ap, ubf(U.y & 0xffffu), bp);
            p[t][3] = fmaf(ap, __uint_as_float(U.y & 0xffff0000u), bp);
        }
        const float4* wr = (const float4*)&wld[c * 32];
        #pragma unroll
        for (int t = 0; t < 4; t++) {
            float4 wa = wr[t * 2], wb = wr[t * 2 + 1];
            #pragma unroll
            for (int s = 0; s < 4; s++) {
                float pv = p[t][s];
                acc[0][s] += wa.x * pv; acc[1][s] += wa.y * pv;
                acc[2][s] += wa.z * pv; acc[3][s] += wa.w * pv;
                acc[4][s] += wb.x * pv; acc[5][s] += wb.y * pv;
                acc[6][s] += wb.z * pv; acc[7][s] += wb.w * pv;
            }
        }
    }

    #pragma unroll
    for (int o = 0; o < 8; o++) {
        float v0 = LRELU(acc[o][0]), v1 = LRELU(acc[o][1]);
        float v2 = LRELU(acc[o][2]), v3 = LRELU(acc[o][3]);
        uint2 st = { bfr(v0) | (bfr(v1) << 16), bfr(v2) | (bfr(v3) << 16) };
        *(uint2*)(y3b + (size_t)(o * 48 + pos) * 8192 + sb) = st;
        float sv = v0 + v1 + v2 + v3;
        float sqv = v0 * v0 + v1 * v1 + v2 * v2 + v3 * v3;
        #pragma unroll
        for (int m = 32; m > 0; m >>= 1) {
            sv  += __shfl_xor(sv, m, 64);
            sqv += __shfl_xor(sqv, m, 64);
        }
        if (lane == 0) { atomicAdd(&red[o], sv); atomicAdd(&red[8 + o], sqv); }
    }
    __syncthreads();
    if (tid < 16) atomicAdd(&stats[48 + tid], red[tid]);
}

// ---------------- k4: BN3 + transpose ----------------
__global__ __launch_bounds__(256) void k4_out(
    const unsigned short* __restrict__ y3b,
    const float* __restrict__ g3, const float* __restrict__ be3,
    float* __restrict__ stats, float* __restrict__ out)
{
    __shared__ unsigned short tile[64][66];
    __shared__ float a3[8], b3[8];
    const int unit = blockIdx.x;         // 768 = 24 (6 ftiles x 4 sub) x 32 chunks
    const int tid = threadIdx.x;
    const int chunkS = unit & 31, yy = unit >> 5;
    const int ftile = yy >> 2, sub = yy & 3;
    const int fbase = ftile * 64;
    const int sbase = chunkS * 256 + sub * 64;

    if (tid < 8) {
        float m = aload(&stats[48 + tid]) * (1.0f / 393216.0f);
        float v = aload(&stats[56 + tid]) * (1.0f / 393216.0f) - m * m;
        float a = g3[tid] * rsqrtf(v + 1e-5f);
        a3[tid] = a; b3[tid] = be3[tid] - a * m;
    }
    __syncthreads();

    #pragma unroll
    for (int rep = 0; rep < 16; rep++) {
        int idx = rep * 256 + tid;
        int f = idx >> 6, s = idx & 63;
        tile[f][s] = y3b[(size_t)(fbase + f) * 8192 + sbase + s];
    }
    __syncthreads();
    #pragma unroll
    for (int rep = 0; rep < 16; rep++) {
        int idx = rep * 256 + tid;
        int s = idx >> 6, f = idx & 63;
        int ff = fbase + f;
        int o = ff / 48;
        float x = ubf((unsigned)tile[f][s]);
        out[(size_t)(sbase + s) * 384 + ff] = a3[o] * x + b3[o];
    }
}

extern "C" void kernel_launch(void* const* d_in, const int* in_sizes, int n_in,
                              void* d_out, int out_size, void* d_ws, size_t ws_size,
                              hipStream_t stream) {
    const float* image   = (const float*)d_in[0];
    const float* conv1_w = (const float*)d_in[1];
    const float* conv1_b = (const float*)d_in[2];
    const float* lc1_w   = (const float*)d_in[3];
    const float* lc1_b   = (const float*)d_in[4];
    const float* lc2_w   = (const float*)d_in[5];
    const float* lc2_b   = (const float*)d_in[6];
    const float* lc3_w   = (const float*)d_in[7];
    const float* lc3_b   = (const float*)d_in[8];
    const float* gamma1  = (const float*)d_in[9];
    const float* beta1   = (const float*)d_in[10];
    const float* gamma2  = (const float*)d_in[11];
    const float* beta2   = (const float*)d_in[12];
    const float* gamma3  = (const float*)d_in[13];
    const float* beta3   = (const float*)d_in[14];
    float* outp = (float*)d_out;

    char* wsb = (char*)d_ws;
    float*          stats = (float*)wsb;                       // 1024 B
    unsigned short* y1b   = (unsigned short*)(wsb + 1024);     // 13,107,200 B
    int4*           afg1  = (int4*)(wsb + 13108224);           // 921,600 B
    char*           x1reg = wsb + 14029824;                    // x1 region (aliases y2b/y3b)
    unsigned short* y2b   = (unsigned short*)(wsb + 14029824); // 8,650,752 B (x1 dead by k2)
    unsigned short* y3b   = (unsigned short*)(wsb + 22680576); // 6,291,456 B

    // choose sample passes so x1 (11,520 B/sample) fits in ws
    const size_t bytesPerSamp = 11520;
    int nPass = 1;
    if (ws_size < 14029824ul + 8192ul * bytesPerSamp) nPass = 2;
    if (ws_size < 14029824ul + 4096ul * bytesPerSamp) nPass = 4;
    if (ws_size < 14029824ul + 2048ul * bytesPerSamp) nPass = 8;
    const int spp = 8192 / nPass;
    const int nA  = spp / 16;
    const int nc  = spp / 256;

    unsigned*   x1u = (unsigned*)x1reg;
    const int4* x1v = (const int4*)x1reg;

    for (int p = 0; p < nPass; ++p) {
        const float* imgp = image + (size_t)p * spp * 90;
        kprep<<<dim3(p == 0 ? nA + 51 : nA), dim3(256), 0, stream>>>(
            imgp, conv1_w, conv1_b, lc1_w, x1u, afg1, stats, nA, p == 0 ? 1 : 0, spp);
        k1_lc1<<<dim3(50 * nc), dim3(256), 0, stream>>>(
            x1v, afg1, lc1_b, y1b, stats, p * spp, spp, nc);
    }
    k2_lc2<<<dim3(528), dim3(256), 0, stream>>>(y1b, lc2_w, lc2_b,
                                                gamma1, beta1, y2b, stats);
    k3_lc3<<<dim3(384), dim3(256), 0, stream>>>(y2b, lc3_w, lc3_b,
                                                gamma2, beta2, y3b, stats);
    k4_out<<<dim3(768), dim3(256), 0, stream>>>(y3b, gamma3, beta3, stats, outp);
}

// Round 10
// 192.856 us; speedup vs baseline: 1.1462x; 1.0044x over previous
//
#include <hip/hip_runtime.h>

// Discriminator pipeline, R10.
// R9 post-mortem: compiler sank the 18-deep register load pipeline (VGPR=48)
// -> k1 still latency-bound. R10: k1 uses global_load_lds DMA (outstanding
// loads live in the vmcnt queue, not VGPRs): per-wave private 4-slot x 4KB
// LDS ring, 18 stages (tap x h), prologue 4 stages in flight, per stage:
// s_waitcnt vmcnt(N) -> 4 swizzled ds_read_b128 -> 4 MFMA -> DMA stage s+4.
// XOR swizzle (qq' = q ^ ((samp>>1)&3)) applied on the DMA SOURCE mapping so
// B-frag reads are 2-way-free (padding illegal under DMA lane*16 layout).
// A-frags in registers (18 x int4). No barriers in the k1 main loop.
//  kprep: conv1+lrelu -> x1 bf16 slabs [(hw,h)][samp][ch32]; pass0: A-frags+stats.
//  k2/k3/k4 unchanged from R9.

typedef float  f32x4 __attribute__((ext_vector_type(4)));
typedef float  f32x2 __attribute__((ext_vector_type(2)));
typedef short  bf16x8 __attribute__((ext_vector_type(8)));

union FR  { int4 i4; bf16x8 bf; unsigned u[4]; };

#define LRELU(v) fmaxf((v), 0.01f * (v))
#define WAITVM(n) asm volatile("s_waitcnt vmcnt(" #n ")" ::: "memory")

static __device__ inline unsigned bfr(float f) {              // RNE fp32->bf16
    unsigned u = __float_as_uint(f);
    return (u + 0x7fffu + ((u >> 16) & 1u)) >> 16;
}
static __device__ inline unsigned short bfr16(float f) { return (unsigned short)bfr(f); }
static __device__ inline float ubf(unsigned lo16) { return __uint_as_float(lo16 << 16); }

#if __has_builtin(__builtin_elementwise_fma)
static __device__ inline f32x2 pk_fma(f32x2 a, f32x2 b, f32x2 c) { return __builtin_elementwise_fma(a, b, c); }
#else
static __device__ inline f32x2 pk_fma(f32x2 a, f32x2 b, f32x2 c) { return a * b + c; }
#endif
static __device__ inline f32x2 pk_lrelu(f32x2 v) {
#if __has_builtin(__builtin_elementwise_max)
    return __builtin_elementwise_max(v, v * 0.01f);
#else
    f32x2 r; r.x = LRELU(v.x); r.y = LRELU(v.y); return r;
#endif
}
static __device__ inline float aload(float* p) {
    return __hip_atomic_load(p, __ATOMIC_RELAXED, __HIP_MEMORY_SCOPE_AGENT);
}
static __device__ __forceinline__ void dma16(const void* g, void* l) {
    __builtin_amdgcn_global_load_lds(
        (const __attribute__((address_space(1))) void*)g,
        (__attribute__((address_space(3))) void*)l, 16, 0, 0);
}

// ---------------- kprep: conv1 -> x1 bf16 slabs (+ afg + stats on pass 0) --------
// x1 (u32 units): x1u[((hw*2 + h)*spp + sampLocal)*16 + chpos], packs ch {2chp,2chp+1}
union PrepSM { float imgP[16][110]; float wt[9216]; };   // 36 KB

__global__ __launch_bounds__(256) void kprep(
    const float* __restrict__ imgp,  // image + pass offset*90
    const float* __restrict__ cw,    // conv1_w [64*4]
    const float* __restrict__ cb,    // conv1_b [64]
    const float* __restrict__ lw1,   // lc1_w [16][64][450]
    unsigned* __restrict__ x1u,
    int4* __restrict__ afg1, float* __restrict__ stats,
    int nA, int doAux, int spp)
{
    __shared__ PrepSM sm;
    const int bx = blockIdx.x, tid = threadIdx.x;

    if (bx < nA) {
        const int sb = bx * 16;                      // local sample base (16 samples)
        for (int e = tid; e < 1760; e += 256) ((float*)sm.imgP)[e] = 0.0f;
        __syncthreads();
        for (int e = tid; e < 1440; e += 256) {
            int s = e / 90, hw = e - s * 90;
            int r = hw / 9, c = hw - r * 9;
            sm.imgP[s][r * 10 + c] = imgp[(size_t)sb * 90 + e];
        }
        __syncthreads();

        // thread -> (quad, samp, h, hw-pair): wave writes 64 consecutive uint4
        const int quad = tid & 3, s = (tid >> 2) & 15;
        const int h = (tid >> 6) & 1, hwo = tid >> 7;
        const int ch0 = h * 32 + quad * 8;           // this thread's 8 channels
        f32x2 W00[4], W01[4], W10[4], W11[4], BB[4];
        #pragma unroll
        for (int p = 0; p < 4; ++p) {
            int ca = ch0 + 2 * p, cbn = ca + 1;
            W00[p] = (f32x2){cw[ca * 4 + 0], cw[cbn * 4 + 0]};
            W01[p] = (f32x2){cw[ca * 4 + 1], cw[cbn * 4 + 1]};
            W10[p] = (f32x2){cw[ca * 4 + 2], cw[cbn * 4 + 2]};
            W11[p] = (f32x2){cw[ca * 4 + 3], cw[cbn * 4 + 3]};
            BB[p]  = (f32x2){cb[ca], cb[cbn]};
        }
        const float* ip = sm.imgP[s];
        uint4* x1q = (uint4*)x1u;
        #pragma unroll 3
        for (int it = 0; it < 45; ++it) {
            int hw = it * 2 + hwo;
            int r = hw / 9, c = hw - r * 9;
            float i00 = ip[r * 10 + c],      i01 = ip[r * 10 + c + 1];
            float i10 = ip[r * 10 + c + 10], i11 = ip[r * 10 + c + 11];
            unsigned u[4];
            #pragma unroll
            for (int p = 0; p < 4; ++p) {
                f32x2 v = BB[p];
                v = pk_fma((f32x2)i00, W00[p], v);
                v = pk_fma((f32x2)i01, W01[p], v);
                v = pk_fma((f32x2)i10, W10[p], v);
                v = pk_fma((f32x2)i11, W11[p], v);
                v = pk_lrelu(v);
                u[p] = bfr(v.x) | (bfr(v.y) << 16);
            }
            // XOR-swizzled qq slot so k1's DMA reads dense AND k1's ds_reads
            // are conflict-free: store ch-quad 'quad' at slot quad^((s>>1)&3)?
            // NO: swizzle is applied on k1's DMA source mapping; x1 stays linear.
            x1q[((size_t)(hw * 2 + h) * spp + (sb + s)) * 4 + quad] =
                make_uint4(u[0], u[1], u[2], u[3]);
        }
        return;
    }
    if (!doAux) return;

    const int b2 = bx - nA;
    if (b2 < 50) {                                   // lc1 A-fragments
        const int pos = b2;
        for (int e = tid; e < 9216; e += 256) {
            int pair = e / 9, t = e - 9 * pair;
            sm.wt[e] = lw1[pair * 450 + pos * 9 + t];
        }
        __syncthreads();
        for (int e = tid; e < 1152; e += 256) {
            int l = e & 63, ht = e >> 6;
            int h = (ht >= 9) ? 1 : 0, t = ht - 9 * h;
            int q = l >> 4, o = l & 15;
            unsigned uu[4];
            #pragma unroll
            for (int p = 0; p < 4; ++p) {
                int c0 = 32 * h + 8 * q + 2 * p;
                float a0 = sm.wt[(o * 64 + c0) * 9 + t];
                float a1 = sm.wt[(o * 64 + c0 + 1) * 9 + t];
                uu[p] = bfr(a0) | (bfr(a1) << 16);
            }
            int4 st = { (int)uu[0], (int)uu[1], (int)uu[2], (int)uu[3] };
            afg1[pos * 1152 + e] = st;
        }
    } else if (tid < 64) stats[tid] = 0.0f;
}

// ---------------- k1: lc1 MFMA GEMM with global_load_lds DMA pipeline ----------
__global__ __launch_bounds__(256) void k1_lc1(
    const unsigned char* __restrict__ x1base,  // byte ptr, slab layout
    const int4* __restrict__ afg,
    const float* __restrict__ lb,
    unsigned short* __restrict__ y1b,
    float* __restrict__ stats,
    int sampOff, int spp, int nc)
{
    __shared__ __align__(16) unsigned char ring[4][4][4096];  // [wave][slot][4KB]
    __shared__ float bl[16];
    __shared__ float red[32];

    int pos, chunk;
    {
        int id = blockIdx.x;
        if (nc >= 8) { int k8 = id & 7; int r = id >> 3; pos = r % 50; chunk = (r / 50) * 8 + k8; }
        else         { pos = id % 50; chunk = id / 50; }
    }
    const int oh = pos / 5, ow = pos % 5;
    const int tid = threadIdx.x;
    const int wv = tid >> 6, lane = tid & 63;
    const int lane15 = lane & 15, q = lane >> 4;

    if (tid < 16) bl[tid] = lb[tid * 50 + pos];
    if (tid < 32) red[tid] = 0.0f;
    __syncthreads();

    // A-frags in registers; invalid taps -> zero frag; slab offsets per stage
    FR fa[18];
    int slabOf[18];
    const int sliceStride = spp * 64;                // bytes per (hw,h) slab
    #pragma unroll
    for (int t = 0; t < 9; ++t) {
        int ti = t / 3, tj = t % 3;
        int r = oh + ti - 1, c2 = 2 * ow + tj - 1;
        bool ok = (r >= 0 && r < 10 && c2 >= 0 && c2 < 9);   // block-uniform
        int hw = ok ? (r * 9 + c2) : 0;
        #pragma unroll
        for (int h = 0; h < 2; ++h) {
            int s = 2 * t + h;
            slabOf[s] = (hw * 2 + h) * sliceStride;
            if (ok) fa[s].i4 = afg[pos * 1152 + (h * 9 + t) * 64 + lane];
            else    fa[s].i4 = (int4){0, 0, 0, 0};
        }
    }

    const int sLoc = chunk * 256 + wv * 64;
    const int sAbs = sampOff + sLoc;
    const unsigned char* slicePtr = x1base + (size_t)sLoc * 64;

    // DMA source offsets (per lane, per 1KB instr) with XOR swizzle:
    // LDS 16B-unit u = i*64+lane holds global (samp = u>>2, qq = (u&3)^((samp>>1)&3))
    int gOffL[4];
    #pragma unroll
    for (int i = 0; i < 4; ++i) {
        int u = i * 64 + lane;
        int sampL = u >> 2;
        int qqG = (u & 3) ^ ((sampL >> 1) & 3);
        gOffL[i] = sampL * 64 + qqG * 16;
    }
    // B-frag ds_read offsets (per g): unit = samp*4 + (q ^ ((samp>>1)&3))
    int offB[4];
    #pragma unroll
    for (int g = 0; g < 4; ++g) {
        int s2 = g * 16 + lane15;
        offB[g] = (s2 * 4 + (q ^ ((s2 >> 1) & 3))) * 16;
    }

    WAITVM(0);                                   // drain fa loads: vmcnt clean

    // prologue: stages 0..3 in flight (16 DMA instrs, 16KB per wave)
    #pragma unroll
    for (int s = 0; s < 4; ++s) {
        const unsigned char* sp = slicePtr + slabOf[s];
        #pragma unroll
        for (int i = 0; i < 4; ++i)
            dma16(sp + gOffL[i], &ring[wv][s][i * 1024]);
    }

    f32x4 acc[4];
    #pragma unroll
    for (int g = 0; g < 4; ++g) acc[g] = (f32x4){0.f, 0.f, 0.f, 0.f};

    #pragma unroll
    for (int s = 0; s < 18; ++s) {
        if (s < 15)      { WAITVM(12); }         // stages s+1..s+3 stay in flight
        else if (s == 15){ WAITVM(8);  }
        else if (s == 16){ WAITVM(4);  }
        else             { WAITVM(0);  }
        const int slot = s & 3;
        #pragma unroll
        for (int g = 0; g < 4; ++g) {
            FR fb; fb.i4 = *(const int4*)&ring[wv][slot][offB[g]];
            acc[g] = __builtin_amdgcn_mfma_f32_16x16x32_bf16(fa[s].bf, fb.bf, acc[g], 0, 0, 0);
        }
        if (s + 4 < 18) {
            const unsigned char* sp = slicePtr + slabOf[s + 4];
            #pragma unroll
            for (int i = 0; i < 4; ++i)
                dma16(sp + gOffL[i], &ring[wv][slot][i * 1024]);
        }
    }

    float so[4] = {0, 0, 0, 0}, sq[4] = {0, 0, 0, 0};
    #pragma unroll
    for (int g = 0; g < 4; ++g)
        #pragma unroll
        for (int r = 0; r < 4; ++r) {
            int o = q * 4 + r;
            float v = acc[g][r] + bl[o];
            v = LRELU(v);
            y1b[(size_t)(o * 50 + pos) * 8192 + sAbs + g * 16 + lane15] = bfr16(v);
            so[r] += v; sq[r] += v * v;
        }
    #pragma unroll
    for (int r = 0; r < 4; ++r) {
        #pragma unroll
        for (int m = 1; m < 16; m <<= 1) {
            so[r] += __shfl_xor(so[r], m, 16);
            sq[r] += __shfl_xor(sq[r], m, 16);
        }
        if (lane15 == 0) {
            int o = q * 4 + r;
            atomicAdd(&red[o], so[r]);
            atomicAdd(&red[16 + o], sq[r]);
        }
    }
    __syncthreads();
    if (tid < 32) atomicAdd(&stats[tid], red[tid]);
}

// ---------------- k2: lc2 (VALU fp32, bf16 uint2 IO) ----------------
__global__ __launch_bounds__(256) void k2_lc2(
    const unsigned short* __restrict__ y1b,
    const float* __restrict__ lw2, const float* __restrict__ lb2,
    const float* __restrict__ g1, const float* __restrict__ be1,
    unsigned short* __restrict__ y2b, float* __restrict__ stats)
{
    __shared__ float wld[512];
    __shared__ float a1[16], b1[16], bl[8], red[16];

    const int unit = blockIdx.x;         // 528 = 66 pos x 8 chunks
    const int pos = unit >> 3, chunk = unit & 7;
    const int oh = pos / 6, ow = pos % 6;
    const int tid = threadIdx.x, lane = tid & 63;

    if (tid < 128) {
        const float* src = lw2 + tid * 264 + pos * 4;
        int o = tid >> 4, c = tid & 15;
        #pragma unroll
        for (int k = 0; k < 4; k++) wld[c * 32 + k * 8 + o] = src[k];
    }
    if (tid < 16) {
        float m = aload(&stats[tid]) * (1.0f / 409600.0f);
        float v = aload(&stats[16 + tid]) * (1.0f / 409600.0f) - m * m;
        float a = g1[tid] * rsqrtf(v + 1e-5f);
        a1[tid] = a; b1[tid] = be1[tid] - a * m;
        if (tid < 8) bl[tid] = lb2[tid * 66 + pos];
        red[tid] = 0.0f;
    }
    __syncthreads();

    int base[4]; float kmv[4];
    #pragma unroll
    for (int i = 0; i < 2; i++)
        #pragma unroll
        for (int j = 0; j < 2; j++) {
            int r = oh + i - 1, c2 = ow + j - 1;
            bool ok = (r >= 0 && r < 10 && c2 >= 0 && c2 < 5);
            int rc = min(max(r, 0), 9), cc2 = min(max(c2, 0), 4);
            base[i * 2 + j] = rc * 5 + cc2;
            kmv[i * 2 + j] = ok ? 1.0f : 0.0f;
        }

    const int sb = chunk * 1024 + tid * 4;
    float acc[8][4];
    #pragma unroll
    for (int o = 0; o < 8; o++)
        #pragma unroll
        for (int s = 0; s < 4; s++) acc[o][s] = bl[o];

    #pragma unroll 1
    for (int c = 0; c < 16; c++) {
        float av = a1[c], bv = b1[c];
        float p[4][4];
        #pragma unroll
        for (int t = 0; t < 4; t++) {
            float ap = av * kmv[t], bp = bv * kmv[t];
            uint2 U = *(const uint2*)(y1b + (size_t)(c * 50 + base[t]) * 8192 + sb);
            p[t][0] = fmaf(ap, ubf(U.x & 0xffffu), bp);
            p[t][1] = fmaf(ap, __uint_as_float(U.x & 0xffff0000u), bp);
            p[t][2] = fmaf(ap, ubf(U.y & 0xffffu), bp);
            p[t][3] = fmaf(ap, __uint_as_float(U.y & 0xffff0000u), bp);
        }
        const float4* wr = (const float4*)&wld[c * 32];
        #pragma unroll
        for (int t = 0; t < 4; t++) {
            float4 wa = wr[t * 2], wb = wr[t * 2 + 1];
            #pragma unroll
            for (int s = 0; s < 4; s++) {
                float pv = p[t][s];
                acc[0][s] += wa.x * pv; acc[1][s] += wa.y * pv;
                acc[2][s] += wa.z * pv; acc[3][s] += wa.w * pv;
                acc[4][s] += wb.x * pv; acc[5][s] += wb.y * pv;
                acc[6][s] += wb.z * pv; acc[7][s] += wb.w * pv;
            }
        }
    }

    #pragma unroll
    for (int o = 0; o < 8; o++) {
        float v0 = LRELU(acc[o][0]), v1 = LRELU(acc[o][1]);
        float v2 = LRELU(acc[o][2]), v3 = LRELU(acc[o][3]);
        uint2 st = { bfr(v0) | (bfr(v1) << 16), bfr(v2) | (bfr(v3) << 16) };
        *(uint2*)(y2b + (size_t)(o * 66 + pos) * 8192 + sb) = st;
        float sv = v0 + v1 + v2 + v3;
        float sqv = v0 * v0 + v1 * v1 + v2 * v2 + v3 * v3;
        #pragma unroll
        for (int m = 32; m > 0; m >>= 1) {
            sv  += __shfl_xor(sv, m, 64);
            sqv += __shfl_xor(sqv, m, 64);
        }
        if (lane == 0) { atomicAdd(&red[o], sv); atomicAdd(&red[8 + o], sqv); }
    }
    __syncthreads();
    if (tid < 16) atomicAdd(&stats[32 + tid], red[tid]);
}

// ---------------- k3: lc3 ----------------
__global__ __launch_bounds__(256) void k3_lc3(
    const unsigned short* __restrict__ y2b,
    const float* __restrict__ lw3, const float* __restrict__ lb3,
    const float* __restrict__ g2, const float* __restrict__ be2,
    unsigned short* __restrict__ y3b, float* __restrict__ stats)
{
    __shared__ float wld[256];
    __shared__ float a2[8], b2[8], bl[8], red[16];

    const int unit = blockIdx.x;         // 384 = 48 pos x 8 chunks
    const int pos = unit >> 3, chunk = unit & 7;
    const int oh = pos >> 2, ow = pos & 3;
    const int tid = threadIdx.x, lane = tid & 63;

    if (tid < 64) {
        const float* src = lw3 + tid * 192 + pos * 4;
        int o = tid >> 3, c = tid & 7;
        #pragma unroll
        for (int k = 0; k < 4; k++) wld[c * 32 + k * 8 + o] = src[k];
    }
    if (tid < 16) {
        if (tid < 8) {
            float m = aload(&stats[32 + tid]) * (1.0f / 540672.0f);
            float v = aload(&stats[40 + tid]) * (1.0f / 540672.0f) - m * m;
            float a = g2[tid] * rsqrtf(v + 1e-5f);
            a2[tid] = a; b2[tid] = be2[tid] - a * m;
            bl[tid] = lb3[tid * 48 + pos];
        }
        red[tid] = 0.0f;
    }
    __syncthreads();

    int base[4]; float kmv[4];
    #pragma unroll
    for (int i = 0; i < 2; i++)
        #pragma unroll
        for (int j = 0; j < 2; j++) {
            int r = oh + i - 1, c2 = 2 * ow + j - 1;
            bool ok = (r >= 0 && r < 11 && c2 >= 0 && c2 < 6);
            int rc = min(max(r, 0), 10), cc2 = min(max(c2, 0), 5);
            base[i * 2 + j] = rc * 6 + cc2;
            kmv[i * 2 + j] = ok ? 1.0f : 0.0f;
        }

    const int sb = chunk * 1024 + tid * 4;
    float acc[8][4];
    #pragma unroll
    for (int o = 0; o < 8; o++)
        #pragma unroll
        for (int s = 0; s < 4; s++) acc[o][s] = bl[o];

    #pragma unroll 1
    for (int c = 0; c < 8; c++) {
        float av = a2[c], bv = b2[c];
        float p[4][4];
        #pragma unroll
        for (int t = 0; t < 4; t++) {
            float ap = av * kmv[t], bp = bv * kmv[t];
            uint2 U = *(const uint2*)(y2b + (size_t)(c * 66 + base[t]) * 8192 + sb);
            p[t][0] = fmaf(ap, ubf(U.x & 0xffffu), bp);
            p[t][1] = fmaf(ap, __uint_as_float(U.x & 0xffff0000u), bp);
            p[t][2] = fmaf(ap, ubf(U.y & 0xffffu), bp);
            p[t][3] = fmaf(ap, __uint_as_float(U.y & 0xffff0000u), bp);
        }
        const float4* wr = (const float4*)&wld[c * 32];
        #pragma unroll
        for (int t = 0; t < 4; t++) {
            float4 wa = wr[t * 2], wb = wr[t * 2 + 1];
            #pragma unroll
            for (int s = 0; s < 4; s++) {
                float pv = p[t][s];
                acc[0][s] += wa.x * pv; acc[1][s] += wa.y * pv;
                acc[2][s] += wa.z * pv; acc[3][s] += wa.w * pv;
                acc[4][s] += wb.x * pv; acc[5][s] += wb.y * pv;
                acc[6][s] += wb.z * pv; acc[7][s] += wb.w * pv;
            }
        }
    }

    #pragma unroll
    for (int o = 0; o < 8; o++) {
        float v0 = LRELU(acc[o][0]), v1 = LRELU(acc[o][1]);
        float v2 = LRELU(acc[o][2]), v3 = LRELU(acc[o][3]);
        uint2 st = { bfr(v0) | (bfr(v1) << 16), bfr(v2) | (bfr(v3) << 16) };
        *(uint2*)(y3b + (size_t)(o * 48 + pos) * 8192 + sb) = st;
        float sv = v0 + v1 + v2 + v3;
        float sqv = v0 * v0 + v1 * v1 + v2 * v2 + v3 * v3;
        #pragma unroll
        for (int m = 32; m > 0; m >>= 1) {
            sv  += __shfl_xor(sv, m, 64);
            sqv += __shfl_xor(sqv, m, 64);
        }
        if (lane == 0) { atomicAdd(&red[o], sv); atomicAdd(&red[8 + o], sqv); }
    }
    __syncthreads();
    if (tid < 16) atomicAdd(&stats[48 + tid], red[tid]);
}

// ---------------- k4: BN3 + transpose ----------------
__global__ __launch_bounds__(256) void k4_out(
    const unsigned short* __restrict__ y3b,
    const float* __restrict__ g3, const float* __restrict__ be3,
    float* __restrict__ stats, float* __restrict__ out)
{
    __shared__ unsigned short tile[64][66];
    __shared__ float a3[8], b3[8];
    const int unit = blockIdx.x;         // 768 = 24 (6 ftiles x 4 sub) x 32 chunks
    const int tid = threadIdx.x;
    const int chunkS = unit & 31, yy = unit >> 5;
    const int ftile = yy >> 2, sub = yy & 3;
    const int fbase = ftile * 64;
    const int sbase = chunkS * 256 + sub * 64;

    if (tid < 8) {
        float m = aload(&stats[48 + tid]) * (1.0f / 393216.0f);
        float v = aload(&stats[56 + tid]) * (1.0f / 393216.0f) - m * m;
        float a = g3[tid] * rsqrtf(v + 1e-5f);
        a3[tid] = a; b3[tid] = be3[tid] - a * m;
    }
    __syncthreads();

    #pragma unroll
    for (int rep = 0; rep < 16; rep++) {
        int idx = rep * 256 + tid;
        int f = idx >> 6, s = idx & 63;
        tile[f][s] = y3b[(size_t)(fbase + f) * 8192 + sbase + s];
    }
    __syncthreads();
    #pragma unroll
    for (int rep = 0; rep < 16; rep++) {
        int idx = rep * 256 + tid;
        int s = idx >> 6, f = idx & 63;
        int ff = fbase + f;
        int o = ff / 48;
        float x = ubf((unsigned)tile[f][s]);
        out[(size_t)(sbase + s) * 384 + ff] = a3[o] * x + b3[o];
    }
}

extern "C" void kernel_launch(void* const* d_in, const int* in_sizes, int n_in,
                              void* d_out, int out_size, void* d_ws, size_t ws_size,
                              hipStream_t stream) {
    const float* image   = (const float*)d_in[0];
    const float* conv1_w = (const float*)d_in[1];
    const float* conv1_b = (const float*)d_in[2];
    const float* lc1_w   = (const float*)d_in[3];
    const float* lc1_b   = (const float*)d_in[4];
    const float* lc2_w   = (const float*)d_in[5];
    const float* lc2_b   = (const float*)d_in[6];
    const float* lc3_w   = (const float*)d_in[7];
    const float* lc3_b   = (const float*)d_in[8];
    const float* gamma1  = (const float*)d_in[9];
    const float* beta1   = (const float*)d_in[10];
    const float* gamma2  = (const float*)d_in[11];
    const float* beta2   = (const float*)d_in[12];
    const float* gamma3  = (const float*)d_in[13];
    const float* beta3   = (const float*)d_in[14];
    float* outp = (float*)d_out;

    char* wsb = (char*)d_ws;
    float*          stats = (float*)wsb;                       // 1024 B
    unsigned short* y1b   = (unsigned short*)(wsb + 1024);     // 13,107,200 B
    int4*           afg1  = (int4*)(wsb + 13108224);           // 921,600 B
    char*           x1reg = wsb + 14029824;                    // x1 region (aliases y2b/y3b)
    unsigned short* y2b   = (unsigned short*)(wsb + 14029824); // 8,650,752 B (x1 dead by k2)
    unsigned short* y3b   = (unsigned short*)(wsb + 22680576); // 6,291,456 B

    // choose sample passes so x1 (11,520 B/sample) fits in ws
    const size_t bytesPerSamp = 11520;
    int nPass = 1;
    if (ws_size < 14029824ul + 8192ul * bytesPerSamp) nPass = 2;
    if (ws_size < 14029824ul + 4096ul * bytesPerSamp) nPass = 4;
    if (ws_size < 14029824ul + 2048ul * bytesPerSamp) nPass = 8;
    const int spp = 8192 / nPass;
    const int nA  = spp / 16;
    const int nc  = spp / 256;

    unsigned* x1u = (unsigned*)x1reg;

    for (int p = 0; p < nPass; ++p) {
        const float* imgp = image + (size_t)p * spp * 90;
        kprep<<<dim3(p == 0 ? nA + 51 : nA), dim3(256), 0, stream>>>(
            imgp, conv1_w, conv1_b, lc1_w, x1u, afg1, stats, nA, p == 0 ? 1 : 0, spp);
        k1_lc1<<<dim3(50 * nc), dim3(256), 0, stream>>>(
            (const unsigned char*)x1reg, afg1, lc1_b, y1b, stats, p * spp, spp, nc);
    }
    k2_lc2<<<dim3(528), dim3(256), 0, stream>>>(y1b, lc2_w, lc2_b,
                                                gamma1, beta1, y2b, stats);
    k3_lc3<<<dim3(384), dim3(256), 0, stream>>>(y2b, lc3_w, lc3_b,
                                                gamma2, beta2, y3b, stats);
    k4_out<<<dim3(768), dim3(256), 0, stream>>>(y3b, gamma3, beta3, stats, outp);
}